// Round 1
// baseline (199.315 us; speedup 1.0000x reference)
//
#include <hip/hip_runtime.h>

typedef unsigned short u16;
typedef unsigned int u32;
typedef unsigned long long u64;

typedef __bf16 bfrag __attribute__((ext_vector_type(8)));
typedef float f32x4 __attribute__((ext_vector_type(4)));

typedef __attribute__((address_space(1))) char* gas1_p;
typedef __attribute__((address_space(3))) char* las3_p;

#define DI __device__ __forceinline__

DI u16 f2bf(float f) {
  u32 u = __float_as_uint(f);
  u += 0x7FFFu + ((u >> 16) & 1u);
  return (u16)(u >> 16);
}
DI float bf2f(u16 h) { return __uint_as_float(((u32)h) << 16); }

DI void gload16(const void* g, void* l) {
  __builtin_amdgcn_global_load_lds((gas1_p)(u64)g, (las3_p)(u32)(u64)l, 16, 0, 0);
}

// ---------------- elementwise split: f32 -> bf16 hi + bf16 lo ----------------
__global__ __launch_bounds__(256) void k_split4(const float4* __restrict__ in,
                                                uint2* __restrict__ hi,
                                                uint2* __restrict__ lo) {
  int i = blockIdx.x * 256 + threadIdx.x;
  float4 v = in[i];
  u16 h0 = f2bf(v.x), h1 = f2bf(v.y), h2 = f2bf(v.z), h3 = f2bf(v.w);
  u16 l0 = f2bf(v.x - bf2f(h0)), l1 = f2bf(v.y - bf2f(h1));
  u16 l2 = f2bf(v.z - bf2f(h2)), l3 = f2bf(v.w - bf2f(h3));
  hi[i] = make_uint2((u32)h0 | ((u32)h1 << 16), (u32)h2 | ((u32)h3 << 16));
  lo[i] = make_uint2((u32)l0 | ((u32)l1 << 16), (u32)l2 | ((u32)l3 << 16));
}

// ------------- split (optional) + transposed split (optional) ----------------
// in: [Z][rows][cols] f32. hi/lo: [Z][rows][cols] bf16. thi/tlo: [Z][cols][rows] bf16.
template <int WH, int WL, int WTH, int WTL>
__global__ __launch_bounds__(256) void k_trsplit(const float* __restrict__ in,
                                                 u16* __restrict__ hi, u16* __restrict__ lo,
                                                 u16* __restrict__ thi, u16* __restrict__ tlo,
                                                 int rows, int cols) {
  __shared__ float tile[32][33];
  const u64 zoff = (u64)blockIdx.z * (u64)rows * (u64)cols;
  const int r = threadIdx.x >> 3, c4 = (threadIdx.x & 7) << 2;
  const int gr = blockIdx.y * 32 + r, gc = blockIdx.x * 32 + c4;
  float4 v = *reinterpret_cast<const float4*>(in + zoff + (u64)gr * cols + gc);
  if constexpr (WH || WL) {
    float fv[4] = {v.x, v.y, v.z, v.w};
    u16 h[4];
#pragma unroll
    for (int j = 0; j < 4; ++j) h[j] = f2bf(fv[j]);
    if constexpr (WH)
      *reinterpret_cast<uint2*>(hi + zoff + (u64)gr * cols + gc) =
          make_uint2((u32)h[0] | ((u32)h[1] << 16), (u32)h[2] | ((u32)h[3] << 16));
    if constexpr (WL) {
      u16 l[4];
#pragma unroll
      for (int j = 0; j < 4; ++j) l[j] = f2bf(fv[j] - bf2f(h[j]));
      *reinterpret_cast<uint2*>(lo + zoff + (u64)gr * cols + gc) =
          make_uint2((u32)l[0] | ((u32)l[1] << 16), (u32)l[2] | ((u32)l[3] << 16));
    }
  }
  tile[r][c4 + 0] = v.x;
  tile[r][c4 + 1] = v.y;
  tile[r][c4 + 2] = v.z;
  tile[r][c4 + 3] = v.w;
  __syncthreads();
  if constexpr (WTH || WTL) {
    const int oc = blockIdx.x * 32 + (threadIdx.x >> 3);
    const int orB = blockIdx.y * 32 + ((threadIdx.x & 7) << 2);
    float wv[4];
#pragma unroll
    for (int j = 0; j < 4; ++j) wv[j] = tile[((threadIdx.x & 7) << 2) + j][threadIdx.x >> 3];
    u16 h[4];
#pragma unroll
    for (int j = 0; j < 4; ++j) h[j] = f2bf(wv[j]);
    if constexpr (WTH)
      *reinterpret_cast<uint2*>(thi + zoff + (u64)oc * rows + orB) =
          make_uint2((u32)h[0] | ((u32)h[1] << 16), (u32)h[2] | ((u32)h[3] << 16));
    if constexpr (WTL) {
      u16 l[4];
#pragma unroll
      for (int j = 0; j < 4; ++j) l[j] = f2bf(wv[j] - bf2f(h[j]));
      *reinterpret_cast<uint2*>(tlo + zoff + (u64)oc * rows + orB) =
          make_uint2((u32)l[0] | ((u32)l[1] << 16), (u32)l[2] | ((u32)l[3] << 16));
    }
  }
}

// ---------------- 128x128-tile bt-GEMM (both operands K-contiguous) ----------
// C[z][m][n] = sum_k A[z][m][k]*B[z][n][k].  X3: A/B given as hi+lo bf16 splits,
// acc += Ah*Bh + Ah*Bl + Al*Bh (fp32 MFMA accum).  SPLITOUT: write C as bf16 hi/lo.
template <int X3, int SPLITOUT>
__global__ __launch_bounds__(256, 2) void k_gemm_bt(
    const u16* __restrict__ Ah, const u16* __restrict__ Al,
    const u16* __restrict__ Bh, const u16* __restrict__ Bl,
    float* __restrict__ Cf, u16* __restrict__ Chi, u16* __restrict__ Clo,
    int M, int N, int K, u64 aStride, int aMask, u64 bStride, u64 cStride) {
  __shared__ u16 lds[(X3 ? 4 : 2) * 4096];
  const int tid = threadIdx.x, lane = tid & 63, wid = tid >> 6;
  const int z = blockIdx.z;
  const u64 aOff = (u64)(z & aMask) * aStride;
  const u64 bOff = (u64)z * bStride;
  const u16* gA = Ah + aOff + (u64)blockIdx.y * 128u * (u32)K;
  const u16* gB = Bh + bOff + (u64)blockIdx.x * 128u * (u32)K;
  const u16* gAl = nullptr;
  const u16* gBl = nullptr;
  if constexpr (X3) {
    gAl = Al + aOff + (u64)blockIdx.y * 128u * (u32)K;
    gBl = Bl + bOff + (u64)blockIdx.x * 128u * (u32)K;
  }
  const int wr = wid >> 1, wc = wid & 1;
  f32x4 acc[4][4];
#pragma unroll
  for (int a = 0; a < 4; ++a)
#pragma unroll
    for (int b = 0; b < 4; ++b) acc[a][b] = (f32x4){0.f, 0.f, 0.f, 0.f};
  const int aFr = (wr * 64 + (lane & 15)) * 32 + (lane >> 4) * 8;
  const int bFr = (wc * 64 + (lane & 15)) * 32 + (lane >> 4) * 8;
  constexpr int AH0 = 0, BH0 = 4096, AL0 = 8192, BL0 = 12288;

  for (int k0 = 0; k0 < K; k0 += 32) {
#pragma unroll
    for (int call = 0; call < 2; ++call) {
      const int c = call * 256 + wid * 64 + lane;
      const u64 gofs = (u64)(c >> 2) * (u32)K + (u32)k0 + (u32)((c & 3) << 3);
      const int lofs = (call * 256 + wid * 64) * 8;
      gload16(gA + gofs, &lds[AH0 + lofs]);
      gload16(gB + gofs, &lds[BH0 + lofs]);
      if constexpr (X3) {
        gload16(gAl + gofs, &lds[AL0 + lofs]);
        gload16(gBl + gofs, &lds[BL0 + lofs]);
      }
    }
    __syncthreads();
    bfrag ah[4], bh[4], al[4], bl[4];
#pragma unroll
    for (int f = 0; f < 4; ++f) {
      ah[f] = *reinterpret_cast<const bfrag*>(&lds[AH0 + aFr + f * 512]);
      bh[f] = *reinterpret_cast<const bfrag*>(&lds[BH0 + bFr + f * 512]);
      if constexpr (X3) {
        al[f] = *reinterpret_cast<const bfrag*>(&lds[AL0 + aFr + f * 512]);
        bl[f] = *reinterpret_cast<const bfrag*>(&lds[BL0 + bFr + f * 512]);
      }
    }
#pragma unroll
    for (int fm = 0; fm < 4; ++fm)
#pragma unroll
      for (int fn = 0; fn < 4; ++fn) {
        acc[fm][fn] = __builtin_amdgcn_mfma_f32_16x16x32_bf16(ah[fm], bh[fn], acc[fm][fn], 0, 0, 0);
        if constexpr (X3) {
          acc[fm][fn] = __builtin_amdgcn_mfma_f32_16x16x32_bf16(ah[fm], bl[fn], acc[fm][fn], 0, 0, 0);
          acc[fm][fn] = __builtin_amdgcn_mfma_f32_16x16x32_bf16(al[fm], bh[fn], acc[fm][fn], 0, 0, 0);
        }
      }
    __syncthreads();
  }

  const u64 cOff = (u64)z * cStride;
  const int rB = blockIdx.y * 128 + wr * 64 + (lane >> 4) * 4;
  const int cB = blockIdx.x * 128 + wc * 64 + (lane & 15);
#pragma unroll
  for (int fm = 0; fm < 4; ++fm)
#pragma unroll
    for (int fn = 0; fn < 4; ++fn)
#pragma unroll
      for (int j = 0; j < 4; ++j) {
        const int rr = rB + fm * 16 + j, cc = cB + fn * 16;
        const u64 ci = cOff + (u64)rr * (u32)N + (u32)cc;
        float v = acc[fm][fn][j];
        if constexpr (SPLITOUT) {
          u16 h = f2bf(v);
          Chi[ci] = h;
          Clo[ci] = f2bf(v - bf2f(h));
        } else {
          Cf[ci] = v;
        }
      }
}

// ---------------- softmax over s (one wave per row), +mask, fp32 -> bf16 -----
__global__ __launch_bounds__(256) void k_softmax(const float* __restrict__ sc,
                                                 const float* __restrict__ mask,
                                                 u16* __restrict__ attn) {
  const int row = blockIdx.x * 4 + (threadIdx.x >> 6);  // over N*B*T = 16384
  const int lane = threadIdx.x & 63;
  const int z = row >> 9, t = row & 511, b = z & 7;
  const float* srow = sc + (u64)row * 512 + lane * 8;
  const float* mrow = mask + ((u64)(b * 512 + t)) * 512 + lane * 8;
  float4 s0 = *reinterpret_cast<const float4*>(srow);
  float4 s1 = *reinterpret_cast<const float4*>(srow + 4);
  float4 m0 = *reinterpret_cast<const float4*>(mrow);
  float4 m1 = *reinterpret_cast<const float4*>(mrow + 4);
  float x[8] = {s0.x + m0.x, s0.y + m0.y, s0.z + m0.z, s0.w + m0.w,
                s1.x + m1.x, s1.y + m1.y, s1.z + m1.z, s1.w + m1.w};
  float mx = x[0];
#pragma unroll
  for (int j = 1; j < 8; ++j) mx = fmaxf(mx, x[j]);
#pragma unroll
  for (int off = 32; off > 0; off >>= 1) mx = fmaxf(mx, __shfl_xor(mx, off));
  float sum = 0.f;
#pragma unroll
  for (int j = 0; j < 8; ++j) {
    x[j] = __expf(x[j] - mx);
    sum += x[j];
  }
#pragma unroll
  for (int off = 32; off > 0; off >>= 1) sum += __shfl_xor(sum, off);
  const float inv = 1.f / sum;
  u32 o[4];
#pragma unroll
  for (int j = 0; j < 4; ++j) {
    u16 e0 = f2bf(x[2 * j] * inv), e1 = f2bf(x[2 * j + 1] * inv);
    o[j] = (u32)e0 | ((u32)e1 << 16);
  }
  *reinterpret_cast<uint4*>(attn + (u64)row * 512 + lane * 8) = make_uint4(o[0], o[1], o[2], o[3]);
}

// -----------------------------------------------------------------------------
extern "C" void kernel_launch(void* const* d_in, const int* in_sizes, int n_in,
                              void* d_out, int out_size, void* d_ws, size_t ws_size,
                              hipStream_t stream) {
  // N=4, B=8, T=512, S=512, E=1024, R=1024
  const float* q = (const float*)d_in[0];    // [1,8,512,1024]
  const float* kvs = (const float*)d_in[1];  // [4,8,512,1024]
  const float* mask = (const float*)d_in[2]; // [1,8,512,512]
  const float* Wk = (const float*)d_in[3];   // [1024,1024]  (bk unused: constant over s)
  float* out = (float*)d_out;                // [4,8,512,1024]

  char* w = (char*)d_ws;
  u16* q_hi = (u16*)(w + 0);            //  8 MiB  [4096][1024]
  u16* q_lo = (u16*)(w + 8388608);      //  8 MiB
  u16* attn = (u16*)(w + 0);            // 16 MiB  [32][512][512]  (aliases q_hi/q_lo, dead by then)
  u16* wkt_hi = (u16*)(w + 16777216);   //  2 MiB  [1024(r)][1024(e)]
  u16* wkt_lo = (u16*)(w + 18874368);   //  2 MiB
  u16* qp_hi = (u16*)(w + 20971520);    //  8 MiB  [8][512][1024]  (b,t,r)
  u16* qp_lo = (u16*)(w + 29360128);    //  8 MiB
  u16* kv_hi = (u16*)(w + 37748736);    // 32 MiB  [32][512][1024] (z,s,r)
  u16* kv_lo = (u16*)(w + 71303168);    // 32 MiB
  u16* kvt_hi = (u16*)(w + 104857600);  // 32 MiB  [32][1024][512] (z,r,s)
  float* sc = (float*)(w + 138412032);  // 32 MiB  [32][512][512]  (z,t,s)
  // total ws use: 171,966,464 bytes

  // 1) split q into hi/lo bf16
  k_split4<<<dim3(4096), dim3(256), 0, stream>>>((const float4*)q, (uint2*)q_hi, (uint2*)q_lo);
  // 2) Wk [e][r] -> transposed split wkt[r][e] hi/lo
  k_trsplit<0, 0, 1, 1><<<dim3(32, 32, 1), dim3(256), 0, stream>>>(
      Wk, (u16*)nullptr, (u16*)nullptr, wkt_hi, wkt_lo, 1024, 1024);
  // 3) kvs -> straight split hi/lo [s][r] + transposed hi [r][s]
  k_trsplit<1, 1, 1, 0><<<dim3(32, 16, 32), dim3(256), 0, stream>>>(
      kvs, kv_hi, kv_lo, kvt_hi, (u16*)nullptr, 512, 1024);
  // 4) qproj[bt][r] = q[bt][e] * wkt[r][e]  (bf16x3, split-output)
  k_gemm_bt<1, 1><<<dim3(8, 32, 1), dim3(256), 0, stream>>>(
      q_hi, q_lo, wkt_hi, wkt_lo, (float*)nullptr, qp_hi, qp_lo,
      4096, 1024, 1024, (u64)0, 0, (u64)0, (u64)0);
  // 5) scores[z][t][s] = qp[b][t][r] * kv[z][s][r]  (bf16x3, fp32 out)
  k_gemm_bt<1, 0><<<dim3(4, 4, 32), dim3(256), 0, stream>>>(
      qp_hi, qp_lo, kv_hi, kv_lo, sc, (u16*)nullptr, (u16*)nullptr,
      512, 512, 1024, (u64)524288, 7, (u64)524288, (u64)262144);
  // 6) softmax(scores + mask) -> attn bf16
  k_softmax<<<dim3(4096), dim3(256), 0, stream>>>(sc, mask, attn);
  // 7) out[z][t][r] = attn[z][t][s] * kvt[z][r][s]  (bf16, fp32 out)
  k_gemm_bt<0, 0><<<dim3(8, 4, 32), dim3(256), 0, stream>>>(
      attn, (u16*)nullptr, kvt_hi, (u16*)nullptr, out, (u16*)nullptr, (u16*)nullptr,
      512, 1024, 512, (u64)262144, 31, (u64)524288, (u64)524288);

  (void)in_sizes; (void)n_in; (void)out_size; (void)ws_size;
}

// Round 2
// 176.982 us; speedup vs baseline: 1.1262x; 1.1262x over previous
//
#include <hip/hip_runtime.h>

typedef unsigned short u16;
typedef unsigned int u32;
typedef unsigned long long u64;

typedef __bf16 bfrag __attribute__((ext_vector_type(8)));
typedef float f32x4 __attribute__((ext_vector_type(4)));

typedef __attribute__((address_space(1))) char* gas1_p;
typedef __attribute__((address_space(3))) char* las3_p;

#define DI __device__ __forceinline__

DI u16 f2bf(float f) {
  u32 u = __float_as_uint(f);
  u += 0x7FFFu + ((u >> 16) & 1u);
  return (u16)(u >> 16);
}
DI float bf2f(u16 h) { return __uint_as_float(((u32)h) << 16); }

DI void gload16(const void* g, void* l) {
  __builtin_amdgcn_global_load_lds((gas1_p)(u64)g, (las3_p)(u32)(u64)l, 16, 0, 0);
}

// ---------------- elementwise split: f32 -> bf16 hi + bf16 lo ----------------
__global__ __launch_bounds__(256) void k_split4(const float4* __restrict__ in,
                                                uint2* __restrict__ hi,
                                                uint2* __restrict__ lo) {
  int i = blockIdx.x * 256 + threadIdx.x;
  float4 v = in[i];
  u16 h0 = f2bf(v.x), h1 = f2bf(v.y), h2 = f2bf(v.z), h3 = f2bf(v.w);
  u16 l0 = f2bf(v.x - bf2f(h0)), l1 = f2bf(v.y - bf2f(h1));
  u16 l2 = f2bf(v.z - bf2f(h2)), l3 = f2bf(v.w - bf2f(h3));
  hi[i] = make_uint2((u32)h0 | ((u32)h1 << 16), (u32)h2 | ((u32)h3 << 16));
  lo[i] = make_uint2((u32)l0 | ((u32)l1 << 16), (u32)l2 | ((u32)l3 << 16));
}

// ------- 64x64 tile: straight split (hi/lo) and/or transposed (thi/tlo) ------
// in: [Z][rows][cols] f32. hi/lo: [Z][rows][cols] bf16. thi/tlo: [Z][cols][rows].
// All global IO is 16B per thread.
template <int WH, int WTH, int WTL>
__global__ __launch_bounds__(256) void k_trsplit64(const float* __restrict__ in,
                                                   u16* __restrict__ hi, u16* __restrict__ lo,
                                                   u16* __restrict__ thi, u16* __restrict__ tlo,
                                                   int rows, int cols) {
  __shared__ float tile[64][65];
  const u64 zoff = (u64)blockIdx.z * (u64)rows * (u64)cols;
  const int r0 = threadIdx.x >> 4;         // 0..15
  const int c4 = (threadIdx.x & 15) << 2;  // 0..60
  const float* src = in + zoff + (u64)(blockIdx.y * 64 + r0) * cols + blockIdx.x * 64 + c4;
#pragma unroll
  for (int p = 0; p < 4; ++p) {
    float4 v = *reinterpret_cast<const float4*>(src + (u64)(p * 16) * cols);
    tile[r0 + p * 16][c4 + 0] = v.x;
    tile[r0 + p * 16][c4 + 1] = v.y;
    tile[r0 + p * 16][c4 + 2] = v.z;
    tile[r0 + p * 16][c4 + 3] = v.w;
  }
  __syncthreads();
  if constexpr (WH) {
    const int rr = threadIdx.x >> 3;        // 0..31
    const int cc = (threadIdx.x & 7) << 3;  // 0..56
#pragma unroll
    for (int p = 0; p < 2; ++p) {
      const int r = rr + p * 32;
      u32 h[4], l[4];
#pragma unroll
      for (int j = 0; j < 4; ++j) {
        float a = tile[r][cc + 2 * j], b = tile[r][cc + 2 * j + 1];
        u16 ha = f2bf(a), hb = f2bf(b);
        h[j] = (u32)ha | ((u32)hb << 16);
        l[j] = (u32)f2bf(a - bf2f(ha)) | ((u32)f2bf(b - bf2f(hb)) << 16);
      }
      const u64 o = zoff + (u64)(blockIdx.y * 64 + r) * cols + blockIdx.x * 64 + cc;
      *reinterpret_cast<uint4*>(hi + o) = make_uint4(h[0], h[1], h[2], h[3]);
      *reinterpret_cast<uint4*>(lo + o) = make_uint4(l[0], l[1], l[2], l[3]);
    }
  }
  if constexpr (WTH) {
#pragma unroll
    for (int p = 0; p < 2; ++p) {
      const int id = threadIdx.x + p * 256;
      const int col = id >> 3;        // 0..63
      const int s8 = (id & 7) << 3;   // 0..56
      u32 h[4], l[4];
#pragma unroll
      for (int j = 0; j < 4; ++j) {
        float a = tile[s8 + 2 * j][col], b = tile[s8 + 2 * j + 1][col];
        u16 ha = f2bf(a), hb = f2bf(b);
        h[j] = (u32)ha | ((u32)hb << 16);
        if constexpr (WTL)
          l[j] = (u32)f2bf(a - bf2f(ha)) | ((u32)f2bf(b - bf2f(hb)) << 16);
      }
      const u64 o = zoff + (u64)(blockIdx.x * 64 + col) * rows + blockIdx.y * 64 + s8;
      *reinterpret_cast<uint4*>(thi + o) = make_uint4(h[0], h[1], h[2], h[3]);
      if constexpr (WTL)
        *reinterpret_cast<uint4*>(tlo + o) = make_uint4(l[0], l[1], l[2], l[3]);
    }
  }
}

// ---------------- 128x128-tile bt-GEMM, double-buffered, XCD-swizzled --------
// C[z][m][n] = sum_k A[z][m][k]*B[z][n][k].  X3: hi+lo splits, 3 MFMA passes.
// ADDMASK: C += Mask[(z&aMask)*cStride + m*N + n].  SPLITOUT: write bf16 hi/lo.
// Launch 1D grid = XT*YT*ZT blocks (divisible by 8); XCD-chunked remap inside.
template <int X3, int SPLITOUT, int ADDMASK, int XT, int YT>
__global__ __launch_bounds__(256, 2) void k_gemm_bt(
    const u16* __restrict__ Ah, const u16* __restrict__ Al,
    const u16* __restrict__ Bh, const u16* __restrict__ Bl,
    float* __restrict__ Cf, u16* __restrict__ Chi, u16* __restrict__ Clo,
    const float* __restrict__ Mask,
    int K, int N, u64 aStride, int aMask, u64 bStride, u64 cStride) {
  constexpr int OPS = X3 ? 4 : 2;
  __shared__ u16 lds[2][OPS][4096];
  const int tid = threadIdx.x, lane = tid & 63, wid = tid >> 6;

  // bijective XCD-chunked swizzle: each XCD gets a contiguous chunk of tiles
  const int g = (blockIdx.x & 7) * (gridDim.x >> 3) + (blockIdx.x >> 3);
  const int z = g / (XT * YT);
  const int rem = g - z * (XT * YT);
  const int ty = rem / XT, tx = rem - (ty * XT);

  const u64 aOff = (u64)(z & aMask) * aStride;
  const u64 bOff = (u64)z * bStride;
  const u16* gA = Ah + aOff + (u64)ty * 128u * (u32)K;
  const u16* gB = Bh + bOff + (u64)tx * 128u * (u32)K;
  const u16* gAl = nullptr;
  const u16* gBl = nullptr;
  if constexpr (X3) {
    gAl = Al + aOff + (u64)ty * 128u * (u32)K;
    gBl = Bl + bOff + (u64)tx * 128u * (u32)K;
  }
  const int wr = wid >> 1, wc = wid & 1;
  f32x4 acc[4][4];
#pragma unroll
  for (int a = 0; a < 4; ++a)
#pragma unroll
    for (int b = 0; b < 4; ++b) acc[a][b] = (f32x4){0.f, 0.f, 0.f, 0.f};
  const int aFr = (wr * 64 + (lane & 15)) * 32 + (lane >> 4) * 8;
  const int bFr = (wc * 64 + (lane & 15)) * 32 + (lane >> 4) * 8;

  auto STAGE = [&](int buf, int k0) {
#pragma unroll
    for (int call = 0; call < 2; ++call) {
      const int c = call * 256 + tid;
      const u64 gofs = (u64)(c >> 2) * (u32)K + (u32)k0 + (u32)((c & 3) << 3);
      const int lofs = (call * 256 + wid * 64) * 8;
      gload16(gA + gofs, &lds[buf][0][lofs]);
      gload16(gB + gofs, &lds[buf][1][lofs]);
      if constexpr (X3) {
        gload16(gAl + gofs, &lds[buf][2][lofs]);
        gload16(gBl + gofs, &lds[buf][3][lofs]);
      }
    }
  };
  auto COMPUTE = [&](int buf) {
    bfrag ah[4], bh[4], al[4], bl[4];
#pragma unroll
    for (int f = 0; f < 4; ++f) {
      ah[f] = *reinterpret_cast<const bfrag*>(&lds[buf][0][aFr + f * 512]);
      bh[f] = *reinterpret_cast<const bfrag*>(&lds[buf][1][bFr + f * 512]);
      if constexpr (X3) {
        al[f] = *reinterpret_cast<const bfrag*>(&lds[buf][2][aFr + f * 512]);
        bl[f] = *reinterpret_cast<const bfrag*>(&lds[buf][3][bFr + f * 512]);
      }
    }
#pragma unroll
    for (int fm = 0; fm < 4; ++fm)
#pragma unroll
      for (int fn = 0; fn < 4; ++fn) {
        acc[fm][fn] = __builtin_amdgcn_mfma_f32_16x16x32_bf16(ah[fm], bh[fn], acc[fm][fn], 0, 0, 0);
        if constexpr (X3) {
          acc[fm][fn] = __builtin_amdgcn_mfma_f32_16x16x32_bf16(ah[fm], bl[fn], acc[fm][fn], 0, 0, 0);
          acc[fm][fn] = __builtin_amdgcn_mfma_f32_16x16x32_bf16(al[fm], bh[fn], acc[fm][fn], 0, 0, 0);
        }
      }
  };

  // 2-phase pipeline: issue next-tile loads BEFORE computing current tile;
  // single barrier per K-step (compiler emits vmcnt(0)+lgkmcnt(0) before it).
  STAGE(0, 0);
  __syncthreads();
  int cur = 0;
  for (int k0 = 32; k0 < K; k0 += 32) {
    STAGE(cur ^ 1, k0);
    COMPUTE(cur);
    __syncthreads();
    cur ^= 1;
  }
  COMPUTE(cur);

  const u64 cOff = (u64)z * cStride;
  const u64 mOff = (u64)(z & aMask) * cStride;
  const int rB = ty * 128 + wr * 64 + (lane >> 4) * 4;
  const int cB = tx * 128 + wc * 64 + (lane & 15);
#pragma unroll
  for (int fm = 0; fm < 4; ++fm)
#pragma unroll
    for (int fn = 0; fn < 4; ++fn)
#pragma unroll
      for (int j = 0; j < 4; ++j) {
        const int rr = rB + fm * 16 + j, cc = cB + fn * 16;
        const u64 ci = cOff + (u64)rr * (u32)N + (u32)cc;
        float v = acc[fm][fn][j];
        if constexpr (ADDMASK) v += Mask[mOff + (u64)rr * (u32)N + (u32)cc];
        if constexpr (SPLITOUT) {
          u16 h = f2bf(v);
          Chi[ci] = h;
          Clo[ci] = f2bf(v - bf2f(h));
        } else {
          Cf[ci] = v;
        }
      }
}

// --------- softmax over s (one wave per row), fp32 in (mask pre-added) -------
__global__ __launch_bounds__(256) void k_softmax(const float* __restrict__ sc,
                                                 u16* __restrict__ attn) {
  const int row = blockIdx.x * 4 + (threadIdx.x >> 6);  // over N*B*T = 16384
  const int lane = threadIdx.x & 63;
  const float* srow = sc + (u64)row * 512 + lane * 8;
  float4 s0 = *reinterpret_cast<const float4*>(srow);
  float4 s1 = *reinterpret_cast<const float4*>(srow + 4);
  float x[8] = {s0.x, s0.y, s0.z, s0.w, s1.x, s1.y, s1.z, s1.w};
  float mx = x[0];
#pragma unroll
  for (int j = 1; j < 8; ++j) mx = fmaxf(mx, x[j]);
#pragma unroll
  for (int off = 32; off > 0; off >>= 1) mx = fmaxf(mx, __shfl_xor(mx, off));
  float sum = 0.f;
#pragma unroll
  for (int j = 0; j < 8; ++j) {
    x[j] = __expf(x[j] - mx);
    sum += x[j];
  }
#pragma unroll
  for (int off = 32; off > 0; off >>= 1) sum += __shfl_xor(sum, off);
  const float inv = 1.f / sum;
  u32 o[4];
#pragma unroll
  for (int j = 0; j < 4; ++j) {
    u16 e0 = f2bf(x[2 * j] * inv), e1 = f2bf(x[2 * j + 1] * inv);
    o[j] = (u32)e0 | ((u32)e1 << 16);
  }
  *reinterpret_cast<uint4*>(attn + (u64)row * 512 + lane * 8) = make_uint4(o[0], o[1], o[2], o[3]);
}

// -----------------------------------------------------------------------------
extern "C" void kernel_launch(void* const* d_in, const int* in_sizes, int n_in,
                              void* d_out, int out_size, void* d_ws, size_t ws_size,
                              hipStream_t stream) {
  // N=4, B=8, T=512, S=512, E=1024, R=1024
  const float* q = (const float*)d_in[0];     // [1,8,512,1024]
  const float* kvs = (const float*)d_in[1];   // [4,8,512,1024]
  const float* mask = (const float*)d_in[2];  // [1,8,512,512]
  const float* Wk = (const float*)d_in[3];    // [1024,1024]  (bk unused: constant over s)
  float* out = (float*)d_out;                 // [4,8,512,1024]

  char* w = (char*)d_ws;
  u16* q_hi = (u16*)(w + 0);            //  8 MiB  [4096][1024]
  u16* q_lo = (u16*)(w + 8388608);      //  8 MiB
  u16* attn = (u16*)(w + 0);            // 16 MiB  [32][512][512]  (aliases q_hi/q_lo, dead by then)
  u16* wkt_hi = (u16*)(w + 16777216);   //  2 MiB  [1024(r)][1024(e)]
  u16* wkt_lo = (u16*)(w + 18874368);   //  2 MiB
  u16* qp_hi = (u16*)(w + 20971520);    //  8 MiB  [8][512][1024]  (b,t,r)
  u16* qp_lo = (u16*)(w + 29360128);    //  8 MiB
  u16* kv_hi = (u16*)(w + 37748736);    // 32 MiB  [32][512][1024] (z,s,r)
  u16* kv_lo = (u16*)(w + 71303168);    // 32 MiB
  u16* kvt_hi = (u16*)(w + 104857600);  // 32 MiB  [32][1024][512] (z,r,s)
  float* sc = (float*)(w + 138412032);  // 32 MiB  [32][512][512]  (z,t,s)

  // 1) split q into hi/lo bf16
  k_split4<<<dim3(4096), dim3(256), 0, stream>>>((const float4*)q, (uint2*)q_hi, (uint2*)q_lo);
  // 2) Wk [e][r] -> transposed split wkt[r][e] hi/lo
  k_trsplit64<0, 1, 1><<<dim3(16, 16, 1), dim3(256), 0, stream>>>(
      Wk, (u16*)nullptr, (u16*)nullptr, wkt_hi, wkt_lo, 1024, 1024);
  // 3) kvs -> straight split hi/lo [s][r] + transposed hi [r][s]
  k_trsplit64<1, 1, 0><<<dim3(16, 8, 32), dim3(256), 0, stream>>>(
      kvs, kv_hi, kv_lo, kvt_hi, (u16*)nullptr, 512, 1024);
  // 4) qproj[bt][r] = q[bt][e] * wkt[r][e]  (bf16x3, split-output); 256 blocks
  k_gemm_bt<1, 1, 0, 8, 32><<<dim3(256), dim3(256), 0, stream>>>(
      q_hi, q_lo, wkt_hi, wkt_lo, (float*)nullptr, qp_hi, qp_lo, (const float*)nullptr,
      1024, 1024, (u64)0, 0, (u64)0, (u64)0);
  // 5) scores[z][t][s] = qp[b][t][r] * kv[z][s][r] + mask  (bf16x3, fp32 out); 512 blocks
  k_gemm_bt<1, 0, 1, 4, 4><<<dim3(512), dim3(256), 0, stream>>>(
      qp_hi, qp_lo, kv_hi, kv_lo, sc, (u16*)nullptr, (u16*)nullptr, mask,
      1024, 512, (u64)524288, 7, (u64)524288, (u64)262144);
  // 6) softmax(sc) -> attn bf16
  k_softmax<<<dim3(4096), dim3(256), 0, stream>>>(sc, attn);
  // 7) out[z][t][r] = attn[z][t][s] * kvt[z][r][s]  (bf16, fp32 out); 1024 blocks
  k_gemm_bt<0, 0, 0, 8, 4><<<dim3(1024), dim3(256), 0, stream>>>(
      attn, (u16*)nullptr, kvt_hi, (u16*)nullptr, out, (u16*)nullptr, (u16*)nullptr,
      (const float*)nullptr, 512, 1024, (u64)262144, 31, (u64)524288, (u64)524288);

  (void)in_sizes; (void)n_in; (void)out_size; (void)ws_size;
}

// Round 3
// 176.028 us; speedup vs baseline: 1.1323x; 1.0054x over previous
//
#include <hip/hip_runtime.h>

typedef unsigned short u16;
typedef unsigned int u32;
typedef unsigned long long u64;

typedef __bf16 bfrag __attribute__((ext_vector_type(8)));
typedef float f32x4 __attribute__((ext_vector_type(4)));

typedef __attribute__((address_space(1))) char* gas1_p;
typedef __attribute__((address_space(3))) char* las3_p;

#define DI __device__ __forceinline__

DI u16 f2bf(float f) {
  u32 u = __float_as_uint(f);
  u += 0x7FFFu + ((u >> 16) & 1u);
  return (u16)(u >> 16);
}
DI float bf2f(u16 h) { return __uint_as_float(((u32)h) << 16); }

DI void gload16(const void* g, void* l) {
  __builtin_amdgcn_global_load_lds((gas1_p)(u64)g, (las3_p)(u32)(u64)l, 16, 0, 0);
}

template <int N>
DI void waitvm() {
  if constexpr (N >= 12)     asm volatile("s_waitcnt vmcnt(12)" ::: "memory");
  else if constexpr (N == 8) asm volatile("s_waitcnt vmcnt(8)" ::: "memory");
  else if constexpr (N == 6) asm volatile("s_waitcnt vmcnt(6)" ::: "memory");
  else if constexpr (N == 4) asm volatile("s_waitcnt vmcnt(4)" ::: "memory");
  else if constexpr (N == 3) asm volatile("s_waitcnt vmcnt(3)" ::: "memory");
  else                       asm volatile("s_waitcnt vmcnt(0)" ::: "memory");
}

// ---------------- elementwise split: f32 -> bf16 hi + bf16 lo ----------------
__global__ __launch_bounds__(256) void k_split4(const float4* __restrict__ in,
                                                uint2* __restrict__ hi,
                                                uint2* __restrict__ lo) {
  int i = blockIdx.x * 256 + threadIdx.x;
  float4 v = in[i];
  u16 h0 = f2bf(v.x), h1 = f2bf(v.y), h2 = f2bf(v.z), h3 = f2bf(v.w);
  u16 l0 = f2bf(v.x - bf2f(h0)), l1 = f2bf(v.y - bf2f(h1));
  u16 l2 = f2bf(v.z - bf2f(h2)), l3 = f2bf(v.w - bf2f(h3));
  hi[i] = make_uint2((u32)h0 | ((u32)h1 << 16), (u32)h2 | ((u32)h3 << 16));
  lo[i] = make_uint2((u32)l0 | ((u32)l1 << 16), (u32)l2 | ((u32)l3 << 16));
}

// ------- 64x64 tile: straight split (hi/lo) and/or transposed (thi/tlo) ------
template <int WH, int WTH, int WTL>
__global__ __launch_bounds__(256) void k_trsplit64(const float* __restrict__ in,
                                                   u16* __restrict__ hi, u16* __restrict__ lo,
                                                   u16* __restrict__ thi, u16* __restrict__ tlo,
                                                   int rows, int cols) {
  __shared__ float tile[64][65];
  const u64 zoff = (u64)blockIdx.z * (u64)rows * (u64)cols;
  const int r0 = threadIdx.x >> 4;
  const int c4 = (threadIdx.x & 15) << 2;
  const float* src = in + zoff + (u64)(blockIdx.y * 64 + r0) * cols + blockIdx.x * 64 + c4;
#pragma unroll
  for (int p = 0; p < 4; ++p) {
    float4 v = *reinterpret_cast<const float4*>(src + (u64)(p * 16) * cols);
    tile[r0 + p * 16][c4 + 0] = v.x;
    tile[r0 + p * 16][c4 + 1] = v.y;
    tile[r0 + p * 16][c4 + 2] = v.z;
    tile[r0 + p * 16][c4 + 3] = v.w;
  }
  __syncthreads();
  if constexpr (WH) {
    const int rr = threadIdx.x >> 3;
    const int cc = (threadIdx.x & 7) << 3;
#pragma unroll
    for (int p = 0; p < 2; ++p) {
      const int r = rr + p * 32;
      u32 h[4], l[4];
#pragma unroll
      for (int j = 0; j < 4; ++j) {
        float a = tile[r][cc + 2 * j], b = tile[r][cc + 2 * j + 1];
        u16 ha = f2bf(a), hb = f2bf(b);
        h[j] = (u32)ha | ((u32)hb << 16);
        l[j] = (u32)f2bf(a - bf2f(ha)) | ((u32)f2bf(b - bf2f(hb)) << 16);
      }
      const u64 o = zoff + (u64)(blockIdx.y * 64 + r) * cols + blockIdx.x * 64 + cc;
      *reinterpret_cast<uint4*>(hi + o) = make_uint4(h[0], h[1], h[2], h[3]);
      *reinterpret_cast<uint4*>(lo + o) = make_uint4(l[0], l[1], l[2], l[3]);
    }
  }
  if constexpr (WTH) {
#pragma unroll
    for (int p = 0; p < 2; ++p) {
      const int id = threadIdx.x + p * 256;
      const int col = id >> 3;
      const int s8 = (id & 7) << 3;
      u32 h[4], l[4];
#pragma unroll
      for (int j = 0; j < 4; ++j) {
        float a = tile[s8 + 2 * j][col], b = tile[s8 + 2 * j + 1][col];
        u16 ha = f2bf(a), hb = f2bf(b);
        h[j] = (u32)ha | ((u32)hb << 16);
        if constexpr (WTL)
          l[j] = (u32)f2bf(a - bf2f(ha)) | ((u32)f2bf(b - bf2f(hb)) << 16);
      }
      const u64 o = zoff + (u64)(blockIdx.x * 64 + col) * rows + blockIdx.y * 64 + s8;
      *reinterpret_cast<uint4*>(thi + o) = make_uint4(h[0], h[1], h[2], h[3]);
      if constexpr (WTL)
        *reinterpret_cast<uint4*>(tlo + o) = make_uint4(l[0], l[1], l[2], l[3]);
    }
  }
}

// ========== deep-pipelined bt-GEMM: BMx128 tile, 8 waves, 3-deep LDS ========
// C[z][m][n] = sum_k A[z][m][k]*B[z][n][k].  BM = FM*32 (256 or 128), BN=128.
// X3: hi+lo bf16 splits, 3 MFMA passes.  ADDMASK: +Mask.  SPLITOUT: bf16 hi/lo.
// K-slot XOR swizzle (kslot ^= (row>>1)&3) applied on BOTH the pre-swizzled
// global source of global_load_lds (LDS stays linear) and the ds_read index.
// Counted-vmcnt pipeline: 3 K-tiles in flight, never vmcnt(0) mid-loop.
template <int X3, int FM, int ADDMASK, int SPLITOUT>
__global__ __launch_bounds__(512) void k_gemm8(
    const u16* __restrict__ Ah, const u16* __restrict__ Al,
    const u16* __restrict__ Bh, const u16* __restrict__ Bl,
    float* __restrict__ Cf, u16* __restrict__ Chi, u16* __restrict__ Clo,
    const float* __restrict__ Mask,
    int K, int N, int mt, int nt,
    u64 aStride, int aMask, u64 bStride, u64 cStride) {
  constexpr int BM = FM * 32;
  constexpr int A_U16 = BM * 32;
  constexpr int B_U16 = 128 * 32;
  constexpr int AL0 = A_U16;                // lo-A offset within tile (u16)
  constexpr int BH0 = A_U16 * (1 + X3);
  constexpr int BL0 = BH0 + B_U16;
  constexpr int TILE = (A_U16 + B_U16) * (1 + X3);
  constexpr int CA = FM / 4;                // A 16B-chunks per thread
  constexpr int L = (CA + 1) * (1 + X3);    // gload_lds per thread per K-tile
  __shared__ u16 lds[3 * TILE];

  const int tid = threadIdx.x, lane = tid & 63;
  const int wid = tid >> 6, wr = wid >> 2, wn = wid & 3;

  // bijective XCD-chunked swizzle (grid divisible by 8)
  const int g = (blockIdx.x & 7) * (gridDim.x >> 3) + (blockIdx.x >> 3);
  const int z = g / (mt * nt);
  const int rem = g - z * (mt * nt);
  const int ty = rem / nt, tx = rem - ty * nt;

  const u64 aOff = (u64)(z & aMask) * aStride;
  const u64 bOff = (u64)z * bStride;
  const u16* gA = Ah + aOff + (u64)ty * (u32)BM * (u32)K;
  const u16* gB = Bh + bOff + (u64)tx * 128u * (u32)K;
  const u16* gAl = nullptr;
  const u16* gBl = nullptr;
  if constexpr (X3) {
    gAl = Al + aOff + (u64)ty * (u32)BM * (u32)K;
    gBl = Bl + bOff + (u64)tx * 128u * (u32)K;
  }

  // per-thread staging offsets (pre-swizzled global k-slot, linear LDS dest)
  u64 aG[CA];
  u32 aLo[CA];
#pragma unroll
  for (int i = 0; i < CA; ++i) {
    const int c = i * 512 + tid;
    const int row = c >> 2, ks = c & 3;
    aG[i] = (u64)row * (u32)K + (u32)((ks ^ ((row >> 1) & 3)) << 3);
    aLo[i] = c << 3;
  }
  const int rowb = tid >> 2, ksb = tid & 3;
  const u64 bG = (u64)rowb * (u32)K + (u32)((ksb ^ ((rowb >> 1) & 3)) << 3);
  const u32 bLo = tid << 3;

  f32x4 acc[FM][2];
#pragma unroll
  for (int m = 0; m < FM; ++m)
#pragma unroll
    for (int n = 0; n < 2; ++n) acc[m][n] = (f32x4){0.f, 0.f, 0.f, 0.f};

  auto STAGE = [&](int bufU, int k0) {
#pragma unroll
    for (int i = 0; i < CA; ++i) {
      gload16(gA + aG[i] + (u32)k0, &lds[bufU + aLo[i]]);
      if constexpr (X3) gload16(gAl + aG[i] + (u32)k0, &lds[bufU + AL0 + aLo[i]]);
    }
    gload16(gB + bG + (u32)k0, &lds[bufU + BH0 + bLo]);
    if constexpr (X3) gload16(gBl + bG + (u32)k0, &lds[bufU + BL0 + bLo]);
  };

  const int swz = (((lane >> 1) & 3) ^ (lane >> 4)) << 3;  // phys k-slot * 8
  auto COMPUTE = [&](int bufU) {
    bfrag ah[FM], alr[FM], bh[2], blr[2];
#pragma unroll
    for (int m = 0; m < FM; ++m) {
      const int idx = bufU + (wr * (BM / 2) + m * 16 + (lane & 15)) * 32 + swz;
      ah[m] = *reinterpret_cast<const bfrag*>(&lds[idx]);
      if constexpr (X3) alr[m] = *reinterpret_cast<const bfrag*>(&lds[idx + AL0]);
    }
#pragma unroll
    for (int n = 0; n < 2; ++n) {
      const int idx = bufU + BH0 + (wn * 32 + n * 16 + (lane & 15)) * 32 + swz;
      bh[n] = *reinterpret_cast<const bfrag*>(&lds[idx]);
      if constexpr (X3) blr[n] = *reinterpret_cast<const bfrag*>(&lds[idx + B_U16]);
    }
    __builtin_amdgcn_s_setprio(1);
#pragma unroll
    for (int m = 0; m < FM; ++m)
#pragma unroll
      for (int n = 0; n < 2; ++n) {
        acc[m][n] = __builtin_amdgcn_mfma_f32_16x16x32_bf16(ah[m], bh[n], acc[m][n], 0, 0, 0);
        if constexpr (X3) {
          acc[m][n] = __builtin_amdgcn_mfma_f32_16x16x32_bf16(ah[m], blr[n], acc[m][n], 0, 0, 0);
          acc[m][n] = __builtin_amdgcn_mfma_f32_16x16x32_bf16(alr[m], bh[n], acc[m][n], 0, 0, 0);
        }
      }
    __builtin_amdgcn_s_setprio(0);
  };

  const int NT = K >> 5;
  STAGE(0, 0);
  STAGE(TILE, 32);
  STAGE(2 * TILE, 64);
  int buf = 0;
  for (int t = 0; t < NT; ++t) {
    const int w = NT - 1 - t;
    if (w >= 2)      waitvm<2 * L>();
    else if (w == 1) waitvm<L>();
    else             waitvm<0>();
    __builtin_amdgcn_s_barrier();
    __builtin_amdgcn_sched_barrier(0);
    COMPUTE(buf * TILE);
    __builtin_amdgcn_s_barrier();
    __builtin_amdgcn_sched_barrier(0);
    if (t + 3 < NT) STAGE(buf * TILE, (t + 3) << 5);
    buf = (buf == 2) ? 0 : buf + 1;
  }

  const u64 cOff = (u64)z * cStride;
  const u64 mOff = (u64)(z & aMask) * cStride;
  const int rB = ty * BM + wr * (BM / 2) + (lane >> 4) * 4;
  const int cB = tx * 128 + wn * 32 + (lane & 15);
#pragma unroll
  for (int m = 0; m < FM; ++m)
#pragma unroll
    for (int n = 0; n < 2; ++n)
#pragma unroll
      for (int j = 0; j < 4; ++j) {
        const int rr = rB + m * 16 + j, cc = cB + n * 16;
        const u64 ci = cOff + (u64)rr * (u32)N + (u32)cc;
        float v = acc[m][n][j];
        if constexpr (ADDMASK) v += Mask[mOff + (u64)rr * (u32)N + (u32)cc];
        if constexpr (SPLITOUT) {
          u16 h = f2bf(v);
          Chi[ci] = h;
          Clo[ci] = f2bf(v - bf2f(h));
        } else {
          Cf[ci] = v;
        }
      }
}

// --------- softmax over s (one wave per row), fp32 in (mask pre-added) -------
__global__ __launch_bounds__(256) void k_softmax(const float* __restrict__ sc,
                                                 u16* __restrict__ attn) {
  const int row = blockIdx.x * 4 + (threadIdx.x >> 6);
  const int lane = threadIdx.x & 63;
  const float* srow = sc + (u64)row * 512 + lane * 8;
  float4 s0 = *reinterpret_cast<const float4*>(srow);
  float4 s1 = *reinterpret_cast<const float4*>(srow + 4);
  float x[8] = {s0.x, s0.y, s0.z, s0.w, s1.x, s1.y, s1.z, s1.w};
  float mx = x[0];
#pragma unroll
  for (int j = 1; j < 8; ++j) mx = fmaxf(mx, x[j]);
#pragma unroll
  for (int off = 32; off > 0; off >>= 1) mx = fmaxf(mx, __shfl_xor(mx, off));
  float sum = 0.f;
#pragma unroll
  for (int j = 0; j < 8; ++j) {
    x[j] = __expf(x[j] - mx);
    sum += x[j];
  }
#pragma unroll
  for (int off = 32; off > 0; off >>= 1) sum += __shfl_xor(sum, off);
  const float inv = 1.f / sum;
  u32 o[4];
#pragma unroll
  for (int j = 0; j < 4; ++j) {
    u16 e0 = f2bf(x[2 * j] * inv), e1 = f2bf(x[2 * j + 1] * inv);
    o[j] = (u32)e0 | ((u32)e1 << 16);
  }
  *reinterpret_cast<uint4*>(attn + (u64)row * 512 + lane * 8) = make_uint4(o[0], o[1], o[2], o[3]);
}

// -----------------------------------------------------------------------------
extern "C" void kernel_launch(void* const* d_in, const int* in_sizes, int n_in,
                              void* d_out, int out_size, void* d_ws, size_t ws_size,
                              hipStream_t stream) {
  // N=4, B=8, T=512, S=512, E=1024, R=1024
  const float* q = (const float*)d_in[0];
  const float* kvs = (const float*)d_in[1];
  const float* mask = (const float*)d_in[2];
  const float* Wk = (const float*)d_in[3];  // bk unused (constant over s)
  float* out = (float*)d_out;

  char* w = (char*)d_ws;
  u16* q_hi = (u16*)(w + 0);
  u16* q_lo = (u16*)(w + 8388608);
  u16* attn = (u16*)(w + 0);            // aliases q_hi/q_lo (dead by then)
  u16* wkt_hi = (u16*)(w + 16777216);
  u16* wkt_lo = (u16*)(w + 18874368);
  u16* qp_hi = (u16*)(w + 20971520);
  u16* qp_lo = (u16*)(w + 29360128);
  u16* kv_hi = (u16*)(w + 37748736);
  u16* kv_lo = (u16*)(w + 71303168);
  u16* kvt_hi = (u16*)(w + 104857600);
  float* sc = (float*)(w + 138412032);

  // 1) split q into hi/lo bf16
  k_split4<<<dim3(4096), dim3(256), 0, stream>>>((const float4*)q, (uint2*)q_hi, (uint2*)q_lo);
  // 2) Wk [e][r] -> transposed split wkt[r][e] hi/lo
  k_trsplit64<0, 1, 1><<<dim3(16, 16, 1), dim3(256), 0, stream>>>(
      Wk, (u16*)nullptr, (u16*)nullptr, wkt_hi, wkt_lo, 1024, 1024);
  // 3) kvs -> straight split hi/lo [s][r] + transposed hi [r][s]
  k_trsplit64<1, 1, 0><<<dim3(16, 8, 32), dim3(256), 0, stream>>>(
      kvs, kv_hi, kv_lo, kvt_hi, (u16*)nullptr, 512, 1024);
  // 4) qproj[bt][r] = q[bt][e] * wkt[r][e]  (bf16x3, split-out); BM=128, 256 blocks
  k_gemm8<1, 4, 0, 1><<<dim3(256), dim3(512), 0, stream>>>(
      q_hi, q_lo, wkt_hi, wkt_lo, (float*)nullptr, qp_hi, qp_lo, (const float*)nullptr,
      1024, 1024, 32, 8, (u64)0, 0, (u64)0, (u64)0);
  // 5) scores[z][t][s] = qp[b][t][r]*kv[z][s][r] + mask  (bf16x3); BM=256, 256 blocks
  k_gemm8<1, 8, 1, 0><<<dim3(256), dim3(512), 0, stream>>>(
      qp_hi, qp_lo, kv_hi, kv_lo, sc, (u16*)nullptr, (u16*)nullptr, mask,
      1024, 512, 2, 4, (u64)524288, 7, (u64)524288, (u64)262144);
  // 6) softmax(sc) -> attn bf16
  k_softmax<<<dim3(4096), dim3(256), 0, stream>>>(sc, attn);
  // 7) out[z][t][r] = attn[z][t][s] * kvt[z][r][s]  (bf16); BM=256, 512 blocks
  k_gemm8<0, 8, 0, 0><<<dim3(512), dim3(512), 0, stream>>>(
      attn, (u16*)nullptr, kvt_hi, (u16*)nullptr, out, (u16*)nullptr, (u16*)nullptr,
      (const float*)nullptr, 512, 1024, 2, 8, (u64)262144, 31, (u64)524288, (u64)524288);

  (void)in_sizes; (void)n_in; (void)out_size; (void)ws_size;
}

// Round 4
// 173.951 us; speedup vs baseline: 1.1458x; 1.0119x over previous
//
#include <hip/hip_runtime.h>

typedef unsigned short u16;
typedef unsigned int u32;
typedef unsigned long long u64;

typedef __bf16 bfrag __attribute__((ext_vector_type(8)));
typedef float f32x4 __attribute__((ext_vector_type(4)));

typedef __attribute__((address_space(1))) char* gas1_p;
typedef __attribute__((address_space(3))) char* las3_p;

#define DI __device__ __forceinline__

DI u16 f2bf(float f) {
  u32 u = __float_as_uint(f);
  u += 0x7FFFu + ((u >> 16) & 1u);
  return (u16)(u >> 16);
}
DI float bf2f(u16 h) { return __uint_as_float(((u32)h) << 16); }

DI void gload16(const void* g, void* l) {
  __builtin_amdgcn_global_load_lds((gas1_p)(u64)g, (las3_p)(u32)(u64)l, 16, 0, 0);
}

// ---------------- elementwise split: f32 -> bf16 hi + bf16 lo ----------------
__global__ __launch_bounds__(256) void k_split4(const float4* __restrict__ in,
                                                uint2* __restrict__ hi,
                                                uint2* __restrict__ lo) {
  int i = blockIdx.x * 256 + threadIdx.x;
  float4 v = in[i];
  u16 h0 = f2bf(v.x), h1 = f2bf(v.y), h2 = f2bf(v.z), h3 = f2bf(v.w);
  u16 l0 = f2bf(v.x - bf2f(h0)), l1 = f2bf(v.y - bf2f(h1));
  u16 l2 = f2bf(v.z - bf2f(h2)), l3 = f2bf(v.w - bf2f(h3));
  hi[i] = make_uint2((u32)h0 | ((u32)h1 << 16), (u32)h2 | ((u32)h3 << 16));
  lo[i] = make_uint2((u32)l0 | ((u32)l1 << 16), (u32)l2 | ((u32)l3 << 16));
}

// ------- 64x64 tile: straight split (hi/lo) and/or transposed (thi/tlo) ------
template <int WH, int WTH, int WTL>
__global__ __launch_bounds__(256) void k_trsplit64(const float* __restrict__ in,
                                                   u16* __restrict__ hi, u16* __restrict__ lo,
                                                   u16* __restrict__ thi, u16* __restrict__ tlo,
                                                   int rows, int cols) {
  __shared__ float tile[64][65];
  const u64 zoff = (u64)blockIdx.z * (u64)rows * (u64)cols;
  const int r0 = threadIdx.x >> 4;
  const int c4 = (threadIdx.x & 15) << 2;
  const float* src = in + zoff + (u64)(blockIdx.y * 64 + r0) * cols + blockIdx.x * 64 + c4;
#pragma unroll
  for (int p = 0; p < 4; ++p) {
    float4 v = *reinterpret_cast<const float4*>(src + (u64)(p * 16) * cols);
    tile[r0 + p * 16][c4 + 0] = v.x;
    tile[r0 + p * 16][c4 + 1] = v.y;
    tile[r0 + p * 16][c4 + 2] = v.z;
    tile[r0 + p * 16][c4 + 3] = v.w;
  }
  __syncthreads();
  if constexpr (WH) {
    const int rr = threadIdx.x >> 3;
    const int cc = (threadIdx.x & 7) << 3;
#pragma unroll
    for (int p = 0; p < 2; ++p) {
      const int r = rr + p * 32;
      u32 h[4], l[4];
#pragma unroll
      for (int j = 0; j < 4; ++j) {
        float a = tile[r][cc + 2 * j], b = tile[r][cc + 2 * j + 1];
        u16 ha = f2bf(a), hb = f2bf(b);
        h[j] = (u32)ha | ((u32)hb << 16);
        l[j] = (u32)f2bf(a - bf2f(ha)) | ((u32)f2bf(b - bf2f(hb)) << 16);
      }
      const u64 o = zoff + (u64)(blockIdx.y * 64 + r) * cols + blockIdx.x * 64 + cc;
      *reinterpret_cast<uint4*>(hi + o) = make_uint4(h[0], h[1], h[2], h[3]);
      *reinterpret_cast<uint4*>(lo + o) = make_uint4(l[0], l[1], l[2], l[3]);
    }
  }
  if constexpr (WTH) {
#pragma unroll
    for (int p = 0; p < 2; ++p) {
      const int id = threadIdx.x + p * 256;
      const int col = id >> 3;
      const int s8 = (id & 7) << 3;
      u32 h[4], l[4];
#pragma unroll
      for (int j = 0; j < 4; ++j) {
        float a = tile[s8 + 2 * j][col], b = tile[s8 + 2 * j + 1][col];
        u16 ha = f2bf(a), hb = f2bf(b);
        h[j] = (u32)ha | ((u32)hb << 16);
        if constexpr (WTL)
          l[j] = (u32)f2bf(a - bf2f(ha)) | ((u32)f2bf(b - bf2f(hb)) << 16);
      }
      const u64 o = zoff + (u64)(blockIdx.x * 64 + col) * rows + blockIdx.y * 64 + s8;
      *reinterpret_cast<uint4*>(thi + o) = make_uint4(h[0], h[1], h[2], h[3]);
      if constexpr (WTL)
        *reinterpret_cast<uint4*>(tlo + o) = make_uint4(l[0], l[1], l[2], l[3]);
    }
  }
}

// ======= 2-phase pipelined bt-GEMM: STAGE(next) || COMPUTE(cur), 1 barrier ===
// C[z][m][n] = sum_k A[z][m][k]*B[z][n][k].  Wave grid WRxWC, wave tile
// (FM*16)x(FN*16).  BM=WR*FM*16, BN=WC*FN*16, BK=32, 2-buf LDS (2 blocks/CU).
// X3: hi+lo bf16 splits, 3 MFMA passes.  ADDMASK: +Mask.  SPLITOUT: bf16 hi/lo.
// K-slot XOR swizzle (kslot ^= (row>>1)&3) on BOTH pre-swizzled global source
// (LDS stays lane-linear for global_load_lds) and the ds_read k-slot.
template <int X3, int FM, int FN, int WR, int WC, int ADDMASK, int SPLITOUT>
__global__ __launch_bounds__(WR * WC * 64, 2) void k_gemm2(
    const u16* __restrict__ Ah, const u16* __restrict__ Al,
    const u16* __restrict__ Bh, const u16* __restrict__ Bl,
    float* __restrict__ Cf, u16* __restrict__ Chi, u16* __restrict__ Clo,
    const float* __restrict__ Mask,
    int K, int N, int mt, int nt,
    u64 aStride, int aMask, u64 bStride, u64 cStride) {
  constexpr int BM = WR * FM * 16, BN = WC * FN * 16;
  constexpr int NTHR = WR * WC * 64;
  constexpr int A_U16 = BM * 32, B_U16 = BN * 32;
  constexpr int AL0 = A_U16;
  constexpr int BH0 = A_U16 * (1 + X3);
  constexpr int TILE = (A_U16 + B_U16) * (1 + X3);
  constexpr int CA = BM * 4 / NTHR;  // A 16B-chunks per thread per K-step
  constexpr int CB = BN * 4 / NTHR;
  __shared__ u16 lds[2 * TILE];

  const int tid = threadIdx.x, lane = tid & 63;
  const int wid = tid >> 6, wr = wid / WC, wc = wid % WC;

  // bijective XCD-chunked swizzle (grid divisible by 8)
  const int g = (blockIdx.x & 7) * (gridDim.x >> 3) + (blockIdx.x >> 3);
  const int z = g / (mt * nt);
  const int rem = g - z * (mt * nt);
  const int ty = rem / nt, tx = rem - ty * nt;

  const u64 aOff = (u64)(z & aMask) * aStride;
  const u64 bOff = (u64)z * bStride;
  const u16* gA = Ah + aOff + (u64)ty * (u32)BM * (u32)K;
  const u16* gB = Bh + bOff + (u64)tx * (u32)BN * (u32)K;
  const u16* gAl = nullptr;
  const u16* gBl = nullptr;
  if constexpr (X3) {
    gAl = Al + aOff + (u64)ty * (u32)BM * (u32)K;
    gBl = Bl + bOff + (u64)tx * (u32)BN * (u32)K;
  }

  // per-thread staging offsets (pre-swizzled global k-slot, linear LDS dest)
  u64 aG[CA];
  u32 aLo[CA];
#pragma unroll
  for (int i = 0; i < CA; ++i) {
    const int c = i * NTHR + tid;
    const int row = c >> 2, ks = c & 3;
    aG[i] = (u64)row * (u32)K + (u32)((ks ^ ((row >> 1) & 3)) << 3);
    aLo[i] = c << 3;
  }
  u64 bG[CB];
  u32 bLo[CB];
#pragma unroll
  for (int i = 0; i < CB; ++i) {
    const int c = i * NTHR + tid;
    const int row = c >> 2, ks = c & 3;
    bG[i] = (u64)row * (u32)K + (u32)((ks ^ ((row >> 1) & 3)) << 3);
    bLo[i] = c << 3;
  }

  f32x4 acc[FM][FN];
#pragma unroll
  for (int m = 0; m < FM; ++m)
#pragma unroll
    for (int n = 0; n < FN; ++n) acc[m][n] = (f32x4){0.f, 0.f, 0.f, 0.f};

  auto STAGE = [&](int bufU, int k0) {
#pragma unroll
    for (int i = 0; i < CA; ++i) {
      gload16(gA + aG[i] + (u32)k0, &lds[bufU + aLo[i]]);
      if constexpr (X3) gload16(gAl + aG[i] + (u32)k0, &lds[bufU + AL0 + aLo[i]]);
    }
#pragma unroll
    for (int i = 0; i < CB; ++i) {
      gload16(gB + bG[i] + (u32)k0, &lds[bufU + BH0 + bLo[i]]);
      if constexpr (X3) gload16(gBl + bG[i] + (u32)k0, &lds[bufU + BH0 + B_U16 + bLo[i]]);
    }
  };

  const int swz = (((lane >> 1) & 3) ^ (lane >> 4)) << 3;  // phys k-slot * 8
  auto COMPUTE = [&](int bufU) {
    bfrag ah[FM], alr[FM], bh[FN], blr[FN];
#pragma unroll
    for (int m = 0; m < FM; ++m) {
      const int idx = bufU + (wr * (FM * 16) + m * 16 + (lane & 15)) * 32 + swz;
      ah[m] = *reinterpret_cast<const bfrag*>(&lds[idx]);
      if constexpr (X3) alr[m] = *reinterpret_cast<const bfrag*>(&lds[idx + AL0]);
    }
#pragma unroll
    for (int n = 0; n < FN; ++n) {
      const int idx = bufU + BH0 + (wc * (FN * 16) + n * 16 + (lane & 15)) * 32 + swz;
      bh[n] = *reinterpret_cast<const bfrag*>(&lds[idx]);
      if constexpr (X3) blr[n] = *reinterpret_cast<const bfrag*>(&lds[idx + B_U16]);
    }
#pragma unroll
    for (int m = 0; m < FM; ++m)
#pragma unroll
      for (int n = 0; n < FN; ++n) {
        acc[m][n] = __builtin_amdgcn_mfma_f32_16x16x32_bf16(ah[m], bh[n], acc[m][n], 0, 0, 0);
        if constexpr (X3) {
          acc[m][n] = __builtin_amdgcn_mfma_f32_16x16x32_bf16(ah[m], blr[n], acc[m][n], 0, 0, 0);
          acc[m][n] = __builtin_amdgcn_mfma_f32_16x16x32_bf16(alr[m], bh[n], acc[m][n], 0, 0, 0);
        }
      }
  };

  const int NT = K >> 5;
  // prologue: stage tile 0, drain, barrier
  STAGE(0, 0);
  asm volatile("s_waitcnt vmcnt(0)" ::: "memory");
  __builtin_amdgcn_s_barrier();
  int buf = 0;
  for (int t = 0; t < NT; ++t) {
    if (t + 1 < NT) STAGE(TILE - buf, (t + 1) << 5);  // stage NEXT while computing
    COMPUTE(buf);
    if (t + 1 < NT) {
      asm volatile("s_waitcnt vmcnt(0)" ::: "memory");  // next tile landed
      __builtin_amdgcn_s_barrier();
      buf = TILE - buf;
    }
  }

  const u64 cOff = (u64)z * cStride;
  const u64 mOff = (u64)(z & aMask) * cStride;
  const int rB = ty * BM + wr * (FM * 16) + (lane >> 4) * 4;
  const int cB = tx * BN + wc * (FN * 16) + (lane & 15);
#pragma unroll
  for (int m = 0; m < FM; ++m)
#pragma unroll
    for (int n = 0; n < FN; ++n)
#pragma unroll
      for (int j = 0; j < 4; ++j) {
        const int rr = rB + m * 16 + j, cc = cB + n * 16;
        const u64 ci = cOff + (u64)rr * (u32)N + (u32)cc;
        float v = acc[m][n][j];
        if constexpr (ADDMASK) v += Mask[mOff + (u64)rr * (u32)N + (u32)cc];
        if constexpr (SPLITOUT) {
          u16 h = f2bf(v);
          Chi[ci] = h;
          Clo[ci] = f2bf(v - bf2f(h));
        } else {
          Cf[ci] = v;
        }
      }
}

// --------- softmax over s (one wave per row), fp32 in (mask pre-added) -------
__global__ __launch_bounds__(256) void k_softmax(const float* __restrict__ sc,
                                                 u16* __restrict__ attn) {
  const int row = blockIdx.x * 4 + (threadIdx.x >> 6);
  const int lane = threadIdx.x & 63;
  const float* srow = sc + (u64)row * 512 + lane * 8;
  float4 s0 = *reinterpret_cast<const float4*>(srow);
  float4 s1 = *reinterpret_cast<const float4*>(srow + 4);
  float x[8] = {s0.x, s0.y, s0.z, s0.w, s1.x, s1.y, s1.z, s1.w};
  float mx = x[0];
#pragma unroll
  for (int j = 1; j < 8; ++j) mx = fmaxf(mx, x[j]);
#pragma unroll
  for (int off = 32; off > 0; off >>= 1) mx = fmaxf(mx, __shfl_xor(mx, off));
  float sum = 0.f;
#pragma unroll
  for (int j = 0; j < 8; ++j) {
    x[j] = __expf(x[j] - mx);
    sum += x[j];
  }
#pragma unroll
  for (int off = 32; off > 0; off >>= 1) sum += __shfl_xor(sum, off);
  const float inv = 1.f / sum;
  u32 o[4];
#pragma unroll
  for (int j = 0; j < 4; ++j) {
    u16 e0 = f2bf(x[2 * j] * inv), e1 = f2bf(x[2 * j + 1] * inv);
    o[j] = (u32)e0 | ((u32)e1 << 16);
  }
  *reinterpret_cast<uint4*>(attn + (u64)row * 512 + lane * 8) = make_uint4(o[0], o[1], o[2], o[3]);
}

// -----------------------------------------------------------------------------
extern "C" void kernel_launch(void* const* d_in, const int* in_sizes, int n_in,
                              void* d_out, int out_size, void* d_ws, size_t ws_size,
                              hipStream_t stream) {
  // N=4, B=8, T=512, S=512, E=1024, R=1024
  const float* q = (const float*)d_in[0];
  const float* kvs = (const float*)d_in[1];
  const float* mask = (const float*)d_in[2];
  const float* Wk = (const float*)d_in[3];  // bk unused (constant over s)
  float* out = (float*)d_out;

  char* w = (char*)d_ws;
  u16* q_hi = (u16*)(w + 0);
  u16* q_lo = (u16*)(w + 8388608);
  u16* attn = (u16*)(w + 0);            // aliases q_hi/q_lo (dead by then)
  u16* wkt_hi = (u16*)(w + 16777216);
  u16* wkt_lo = (u16*)(w + 18874368);
  u16* qp_hi = (u16*)(w + 20971520);
  u16* qp_lo = (u16*)(w + 29360128);
  u16* kv_hi = (u16*)(w + 37748736);
  u16* kv_lo = (u16*)(w + 71303168);
  u16* kvt_hi = (u16*)(w + 104857600);
  float* sc = (float*)(w + 138412032);

  // 1) split q into hi/lo bf16
  k_split4<<<dim3(4096), dim3(256), 0, stream>>>((const float4*)q, (uint2*)q_hi, (uint2*)q_lo);
  // 2) Wk [e][r] -> transposed split wkt[r][e] hi/lo
  k_trsplit64<0, 1, 1><<<dim3(16, 16, 1), dim3(256), 0, stream>>>(
      Wk, (u16*)nullptr, (u16*)nullptr, wkt_hi, wkt_lo, 1024, 1024);
  // 3) kvs -> straight split hi/lo [s][r] + transposed hi [r][s]
  k_trsplit64<1, 1, 0><<<dim3(16, 8, 32), dim3(256), 0, stream>>>(
      kvs, kv_hi, kv_lo, kvt_hi, (u16*)nullptr, 512, 1024);
  // 4) qproj[bt][r] = q[bt][e] * wkt[r][e]  (bf16x3, split-out); 128x128, 256 blocks
  k_gemm2<1, 4, 4, 2, 2, 0, 1><<<dim3(256), dim3(256), 0, stream>>>(
      q_hi, q_lo, wkt_hi, wkt_lo, (float*)nullptr, qp_hi, qp_lo, (const float*)nullptr,
      1024, 1024, 32, 8, (u64)0, 0, (u64)0, (u64)0);
  // 5) scores[z][t][s] = qp[b][t][r]*kv[z][s][r] + mask  (bf16x3); 128x128, 512 blocks
  k_gemm2<1, 4, 4, 2, 2, 1, 0><<<dim3(512), dim3(256), 0, stream>>>(
      qp_hi, qp_lo, kv_hi, kv_lo, sc, (u16*)nullptr, (u16*)nullptr, mask,
      1024, 512, 4, 4, (u64)524288, 7, (u64)524288, (u64)262144);
  // 6) softmax(sc) -> attn bf16
  k_softmax<<<dim3(4096), dim3(256), 0, stream>>>(sc, attn);
  // 7) out[z][t][r] = attn[z][t][s] * kvt[z][r][s]  (bf16); 256x128, 512 blocks
  k_gemm2<0, 8, 4, 2, 2, 0, 0><<<dim3(512), dim3(256), 0, stream>>>(
      attn, (u16*)nullptr, kvt_hi, (u16*)nullptr, out, (u16*)nullptr, (u16*)nullptr,
      (const float*)nullptr, 512, 1024, 2, 8, (u64)262144, 31, (u64)524288, (u64)524288);

  (void)in_sizes; (void)n_in; (void)out_size; (void)ws_size;
}

// Round 5
// 173.162 us; speedup vs baseline: 1.1510x; 1.0046x over previous
//
#include <hip/hip_runtime.h>

typedef unsigned short u16;
typedef unsigned int u32;
typedef unsigned long long u64;

typedef __bf16 bfrag __attribute__((ext_vector_type(8)));
typedef float f32x4 __attribute__((ext_vector_type(4)));

typedef __attribute__((address_space(1))) char* gas1_p;
typedef __attribute__((address_space(3))) char* las3_p;

#define DI __device__ __forceinline__

DI u16 f2bf(float f) {
  u32 u = __float_as_uint(f);
  u += 0x7FFFu + ((u >> 16) & 1u);
  return (u16)(u >> 16);
}
DI float bf2f(u16 h) { return __uint_as_float(((u32)h) << 16); }

DI void gload16(const void* g, void* l) {
  __builtin_amdgcn_global_load_lds((gas1_p)(u64)g, (las3_p)(u32)(u64)l, 16, 0, 0);
}

template <int N>
DI void waitvm() {
  if constexpr (N >= 12)     asm volatile("s_waitcnt vmcnt(12)" ::: "memory");
  else if constexpr (N == 8) asm volatile("s_waitcnt vmcnt(8)" ::: "memory");
  else if constexpr (N == 6) asm volatile("s_waitcnt vmcnt(6)" ::: "memory");
  else if constexpr (N == 4) asm volatile("s_waitcnt vmcnt(4)" ::: "memory");
  else if constexpr (N == 3) asm volatile("s_waitcnt vmcnt(3)" ::: "memory");
  else                       asm volatile("s_waitcnt vmcnt(0)" ::: "memory");
}

// ---------------- elementwise split: f32 -> bf16 hi + bf16 lo ----------------
__global__ __launch_bounds__(256) void k_split4(const float4* __restrict__ in,
                                                uint2* __restrict__ hi,
                                                uint2* __restrict__ lo) {
  int i = blockIdx.x * 256 + threadIdx.x;
  float4 v = in[i];
  u16 h0 = f2bf(v.x), h1 = f2bf(v.y), h2 = f2bf(v.z), h3 = f2bf(v.w);
  u16 l0 = f2bf(v.x - bf2f(h0)), l1 = f2bf(v.y - bf2f(h1));
  u16 l2 = f2bf(v.z - bf2f(h2)), l3 = f2bf(v.w - bf2f(h3));
  hi[i] = make_uint2((u32)h0 | ((u32)h1 << 16), (u32)h2 | ((u32)h3 << 16));
  lo[i] = make_uint2((u32)l0 | ((u32)l1 << 16), (u32)l2 | ((u32)l3 << 16));
}

// ------- 64x64 tile: straight split (hi/lo) and/or transposed (thi/tlo) ------
template <int WH, int WTH, int WTL>
__global__ __launch_bounds__(256) void k_trsplit64(const float* __restrict__ in,
                                                   u16* __restrict__ hi, u16* __restrict__ lo,
                                                   u16* __restrict__ thi, u16* __restrict__ tlo,
                                                   int rows, int cols) {
  __shared__ float tile[64][65];
  const u64 zoff = (u64)blockIdx.z * (u64)rows * (u64)cols;
  const int r0 = threadIdx.x >> 4;
  const int c4 = (threadIdx.x & 15) << 2;
  const float* src = in + zoff + (u64)(blockIdx.y * 64 + r0) * cols + blockIdx.x * 64 + c4;
#pragma unroll
  for (int p = 0; p < 4; ++p) {
    float4 v = *reinterpret_cast<const float4*>(src + (u64)(p * 16) * cols);
    tile[r0 + p * 16][c4 + 0] = v.x;
    tile[r0 + p * 16][c4 + 1] = v.y;
    tile[r0 + p * 16][c4 + 2] = v.z;
    tile[r0 + p * 16][c4 + 3] = v.w;
  }
  __syncthreads();
  if constexpr (WH) {
    const int rr = threadIdx.x >> 3;
    const int cc = (threadIdx.x & 7) << 3;
#pragma unroll
    for (int p = 0; p < 2; ++p) {
      const int r = rr + p * 32;
      u32 h[4], l[4];
#pragma unroll
      for (int j = 0; j < 4; ++j) {
        float a = tile[r][cc + 2 * j], b = tile[r][cc + 2 * j + 1];
        u16 ha = f2bf(a), hb = f2bf(b);
        h[j] = (u32)ha | ((u32)hb << 16);
        l[j] = (u32)f2bf(a - bf2f(ha)) | ((u32)f2bf(b - bf2f(hb)) << 16);
      }
      const u64 o = zoff + (u64)(blockIdx.y * 64 + r) * cols + blockIdx.x * 64 + cc;
      *reinterpret_cast<uint4*>(hi + o) = make_uint4(h[0], h[1], h[2], h[3]);
      *reinterpret_cast<uint4*>(lo + o) = make_uint4(l[0], l[1], l[2], l[3]);
    }
  }
  if constexpr (WTH) {
#pragma unroll
    for (int p = 0; p < 2; ++p) {
      const int id = threadIdx.x + p * 256;
      const int col = id >> 3;
      const int s8 = (id & 7) << 3;
      u32 h[4], l[4];
#pragma unroll
      for (int j = 0; j < 4; ++j) {
        float a = tile[s8 + 2 * j][col], b = tile[s8 + 2 * j + 1][col];
        u16 ha = f2bf(a), hb = f2bf(b);
        h[j] = (u32)ha | ((u32)hb << 16);
        if constexpr (WTL)
          l[j] = (u32)f2bf(a - bf2f(ha)) | ((u32)f2bf(b - bf2f(hb)) << 16);
      }
      const u64 o = zoff + (u64)(blockIdx.x * 64 + col) * rows + blockIdx.y * 64 + s8;
      *reinterpret_cast<uint4*>(thi + o) = make_uint4(h[0], h[1], h[2], h[3]);
      if constexpr (WTL)
        *reinterpret_cast<uint4*>(tlo + o) = make_uint4(l[0], l[1], l[2], l[3]);
    }
  }
}

// ======= 2-phase pipelined bt-GEMM (kept for qproj): STAGE(next)||COMPUTE ====
template <int X3, int FM, int FN, int WR, int WC, int ADDMASK, int SPLITOUT>
__global__ __launch_bounds__(WR * WC * 64, 2) void k_gemm2(
    const u16* __restrict__ Ah, const u16* __restrict__ Al,
    const u16* __restrict__ Bh, const u16* __restrict__ Bl,
    float* __restrict__ Cf, u16* __restrict__ Chi, u16* __restrict__ Clo,
    const float* __restrict__ Mask,
    int K, int N, int mt, int nt,
    u64 aStride, int aMask, u64 bStride, u64 cStride) {
  constexpr int BM = WR * FM * 16, BN = WC * FN * 16;
  constexpr int NTHR = WR * WC * 64;
  constexpr int A_U16 = BM * 32, B_U16 = BN * 32;
  constexpr int AL0 = A_U16;
  constexpr int BH0 = A_U16 * (1 + X3);
  constexpr int TILE = (A_U16 + B_U16) * (1 + X3);
  constexpr int CA = BM * 4 / NTHR;
  constexpr int CB = BN * 4 / NTHR;
  __shared__ u16 lds[2 * TILE];

  const int tid = threadIdx.x, lane = tid & 63;
  const int wid = tid >> 6, wr = wid / WC, wc = wid % WC;

  const int g = (blockIdx.x & 7) * (gridDim.x >> 3) + (blockIdx.x >> 3);
  const int z = g / (mt * nt);
  const int rem = g - z * (mt * nt);
  const int ty = rem / nt, tx = rem - ty * nt;

  const u64 aOff = (u64)(z & aMask) * aStride;
  const u64 bOff = (u64)z * bStride;
  const u16* gA = Ah + aOff + (u64)ty * (u32)BM * (u32)K;
  const u16* gB = Bh + bOff + (u64)tx * (u32)BN * (u32)K;
  const u16* gAl = nullptr;
  const u16* gBl = nullptr;
  if constexpr (X3) {
    gAl = Al + aOff + (u64)ty * (u32)BM * (u32)K;
    gBl = Bl + bOff + (u64)tx * (u32)BN * (u32)K;
  }

  u64 aG[CA]; u32 aLo[CA];
#pragma unroll
  for (int i = 0; i < CA; ++i) {
    const int c = i * NTHR + tid;
    const int row = c >> 2, ks = c & 3;
    aG[i] = (u64)row * (u32)K + (u32)((ks ^ ((row >> 1) & 3)) << 3);
    aLo[i] = c << 3;
  }
  u64 bG[CB]; u32 bLo[CB];
#pragma unroll
  for (int i = 0; i < CB; ++i) {
    const int c = i * NTHR + tid;
    const int row = c >> 2, ks = c & 3;
    bG[i] = (u64)row * (u32)K + (u32)((ks ^ ((row >> 1) & 3)) << 3);
    bLo[i] = c << 3;
  }

  f32x4 acc[FM][FN];
#pragma unroll
  for (int m = 0; m < FM; ++m)
#pragma unroll
    for (int n = 0; n < FN; ++n) acc[m][n] = (f32x4){0.f, 0.f, 0.f, 0.f};

  auto STAGE = [&](int bufU, int k0) {
#pragma unroll
    for (int i = 0; i < CA; ++i) {
      gload16(gA + aG[i] + (u32)k0, &lds[bufU + aLo[i]]);
      if constexpr (X3) gload16(gAl + aG[i] + (u32)k0, &lds[bufU + AL0 + aLo[i]]);
    }
#pragma unroll
    for (int i = 0; i < CB; ++i) {
      gload16(gB + bG[i] + (u32)k0, &lds[bufU + BH0 + bLo[i]]);
      if constexpr (X3) gload16(gBl + bG[i] + (u32)k0, &lds[bufU + BH0 + B_U16 + bLo[i]]);
    }
  };

  const int swz = (((lane >> 1) & 3) ^ (lane >> 4)) << 3;
  auto COMPUTE = [&](int bufU) {
    bfrag ah[FM], alr[FM], bh[FN], blr[FN];
#pragma unroll
    for (int m = 0; m < FM; ++m) {
      const int idx = bufU + (wr * (FM * 16) + m * 16 + (lane & 15)) * 32 + swz;
      ah[m] = *reinterpret_cast<const bfrag*>(&lds[idx]);
      if constexpr (X3) alr[m] = *reinterpret_cast<const bfrag*>(&lds[idx + AL0]);
    }
#pragma unroll
    for (int n = 0; n < FN; ++n) {
      const int idx = bufU + BH0 + (wc * (FN * 16) + n * 16 + (lane & 15)) * 32 + swz;
      bh[n] = *reinterpret_cast<const bfrag*>(&lds[idx]);
      if constexpr (X3) blr[n] = *reinterpret_cast<const bfrag*>(&lds[idx + B_U16]);
    }
#pragma unroll
    for (int m = 0; m < FM; ++m)
#pragma unroll
      for (int n = 0; n < FN; ++n) {
        acc[m][n] = __builtin_amdgcn_mfma_f32_16x16x32_bf16(ah[m], bh[n], acc[m][n], 0, 0, 0);
        if constexpr (X3) {
          acc[m][n] = __builtin_amdgcn_mfma_f32_16x16x32_bf16(ah[m], blr[n], acc[m][n], 0, 0, 0);
          acc[m][n] = __builtin_amdgcn_mfma_f32_16x16x32_bf16(alr[m], bh[n], acc[m][n], 0, 0, 0);
        }
      }
  };

  const int NT = K >> 5;
  STAGE(0, 0);
  asm volatile("s_waitcnt vmcnt(0)" ::: "memory");
  __builtin_amdgcn_s_barrier();
  int buf = 0;
  for (int t = 0; t < NT; ++t) {
    if (t + 1 < NT) STAGE(TILE - buf, (t + 1) << 5);
    COMPUTE(buf);
    if (t + 1 < NT) {
      asm volatile("s_waitcnt vmcnt(0)" ::: "memory");
      __builtin_amdgcn_s_barrier();
      buf = TILE - buf;
    }
  }

  const u64 cOff = (u64)z * cStride;
  const u64 mOff = (u64)(z & aMask) * cStride;
  const int rB = ty * BM + wr * (FM * 16) + (lane >> 4) * 4;
  const int cB = tx * BN + wc * (FN * 16) + (lane & 15);
#pragma unroll
  for (int m = 0; m < FM; ++m)
#pragma unroll
    for (int n = 0; n < FN; ++n)
#pragma unroll
      for (int j = 0; j < 4; ++j) {
        const int rr = rB + m * 16 + j, cc = cB + n * 16;
        const u64 ci = cOff + (u64)rr * (u32)N + (u32)cc;
        float v = acc[m][n][j];
        if constexpr (ADDMASK) v += Mask[mOff + (u64)rr * (u32)N + (u32)cc];
        if constexpr (SPLITOUT) {
          u16 h = f2bf(v);
          Chi[ci] = h;
          Clo[ci] = f2bf(v - bf2f(h));
        } else {
          Cf[ci] = v;
        }
      }
}

// ======= depth-3 counted-vmcnt bt-GEMM: BM=256 BN=128, 8 waves, 64x64 tiles ==
// 3 K-tiles in flight; loop-top waits vmcnt(2L) (tile t landed, t+1/t+2 fly).
// No sched_barrier (m141), no setprio (lockstep waves, m190). Swizzle kept.
template <int X3, int ADDMASK, int SPLITOUT, int MINW>
__global__ __launch_bounds__(512, MINW) void k_gemm3(
    const u16* __restrict__ Ah, const u16* __restrict__ Al,
    const u16* __restrict__ Bh, const u16* __restrict__ Bl,
    float* __restrict__ Cf, u16* __restrict__ Chi, u16* __restrict__ Clo,
    const float* __restrict__ Mask,
    int K, int N, int mt, int nt,
    u64 aStride, int aMask, u64 bStride, u64 cStride) {
  constexpr int BM = 256, BN = 128, NTHR = 512;
  constexpr int FM = 4, FN = 4, WC = 2;  // 4Mx2N waves, 64x64 wave tile
  constexpr int A_U16 = BM * 32, B_U16 = BN * 32;
  constexpr int AL0 = A_U16;
  constexpr int BH0 = A_U16 * (1 + X3);
  constexpr int TILE = (A_U16 + B_U16) * (1 + X3);
  constexpr int CA = BM * 4 / NTHR;             // 2
  constexpr int CB = BN * 4 / NTHR;             // 1
  constexpr int L = (CA + CB) * (1 + X3);       // 6 (x3) / 3 (x1)
  __shared__ u16 lds[3 * TILE];

  const int tid = threadIdx.x, lane = tid & 63;
  const int wid = tid >> 6, wr = wid >> 1, wc = wid & 1;

  const int g = (blockIdx.x & 7) * (gridDim.x >> 3) + (blockIdx.x >> 3);
  const int z = g / (mt * nt);
  const int rem = g - z * (mt * nt);
  const int ty = rem / nt, tx = rem - ty * nt;

  const u64 aOff = (u64)(z & aMask) * aStride;
  const u64 bOff = (u64)z * bStride;
  const u16* gA = Ah + aOff + (u64)ty * (u32)BM * (u32)K;
  const u16* gB = Bh + bOff + (u64)tx * (u32)BN * (u32)K;
  const u16* gAl = nullptr;
  const u16* gBl = nullptr;
  if constexpr (X3) {
    gAl = Al + aOff + (u64)ty * (u32)BM * (u32)K;
    gBl = Bl + bOff + (u64)tx * (u32)BN * (u32)K;
  }

  u64 aG[CA]; u32 aLo[CA];
#pragma unroll
  for (int i = 0; i < CA; ++i) {
    const int c = i * NTHR + tid;
    const int row = c >> 2, ks = c & 3;
    aG[i] = (u64)row * (u32)K + (u32)((ks ^ ((row >> 1) & 3)) << 3);
    aLo[i] = c << 3;
  }
  u64 bG[CB]; u32 bLo[CB];
#pragma unroll
  for (int i = 0; i < CB; ++i) {
    const int c = i * NTHR + tid;
    const int row = c >> 2, ks = c & 3;
    bG[i] = (u64)row * (u32)K + (u32)((ks ^ ((row >> 1) & 3)) << 3);
    bLo[i] = c << 3;
  }

  f32x4 acc[FM][FN];
#pragma unroll
  for (int m = 0; m < FM; ++m)
#pragma unroll
    for (int n = 0; n < FN; ++n) acc[m][n] = (f32x4){0.f, 0.f, 0.f, 0.f};

  auto STAGE = [&](int bufU, int k0) {
#pragma unroll
    for (int i = 0; i < CA; ++i) {
      gload16(gA + aG[i] + (u32)k0, &lds[bufU + aLo[i]]);
      if constexpr (X3) gload16(gAl + aG[i] + (u32)k0, &lds[bufU + AL0 + aLo[i]]);
    }
#pragma unroll
    for (int i = 0; i < CB; ++i) {
      gload16(gB + bG[i] + (u32)k0, &lds[bufU + BH0 + bLo[i]]);
      if constexpr (X3) gload16(gBl + bG[i] + (u32)k0, &lds[bufU + BH0 + B_U16 + bLo[i]]);
    }
  };

  const int swz = (((lane >> 1) & 3) ^ (lane >> 4)) << 3;
  auto COMPUTE = [&](int bufU) {
    bfrag ah[FM], alr[FM], bh[FN], blr[FN];
#pragma unroll
    for (int m = 0; m < FM; ++m) {
      const int idx = bufU + (wr * 64 + m * 16 + (lane & 15)) * 32 + swz;
      ah[m] = *reinterpret_cast<const bfrag*>(&lds[idx]);
      if constexpr (X3) alr[m] = *reinterpret_cast<const bfrag*>(&lds[idx + AL0]);
    }
#pragma unroll
    for (int n = 0; n < FN; ++n) {
      const int idx = bufU + BH0 + (wc * 64 + n * 16 + (lane & 15)) * 32 + swz;
      bh[n] = *reinterpret_cast<const bfrag*>(&lds[idx]);
      if constexpr (X3) blr[n] = *reinterpret_cast<const bfrag*>(&lds[idx + B_U16]);
    }
#pragma unroll
    for (int m = 0; m < FM; ++m)
#pragma unroll
      for (int n = 0; n < FN; ++n) {
        acc[m][n] = __builtin_amdgcn_mfma_f32_16x16x32_bf16(ah[m], bh[n], acc[m][n], 0, 0, 0);
        if constexpr (X3) {
          acc[m][n] = __builtin_amdgcn_mfma_f32_16x16x32_bf16(ah[m], blr[n], acc[m][n], 0, 0, 0);
          acc[m][n] = __builtin_amdgcn_mfma_f32_16x16x32_bf16(alr[m], bh[n], acc[m][n], 0, 0, 0);
        }
      }
  };

  const int NT = K >> 5;
  STAGE(0, 0);
  STAGE(TILE, 32);
  STAGE(2 * TILE, 64);
  int buf = 0;
  for (int t = 0; t < NT; ++t) {
    const int w = NT - 1 - t;
    if (w >= 2)      waitvm<2 * L>();
    else if (w == 1) waitvm<L>();
    else             waitvm<0>();
    __builtin_amdgcn_s_barrier();
    COMPUTE(buf);
    __builtin_amdgcn_s_barrier();
    if (t + 3 < NT) STAGE(buf, (t + 3) << 5);
    buf = (buf == 2 * TILE) ? 0 : buf + TILE;
  }

  const u64 cOff = (u64)z * cStride;
  const u64 mOff = (u64)(z & aMask) * cStride;
  const int rB = ty * BM + wr * 64 + (lane >> 4) * 4;
  const int cB = tx * BN + wc * 64 + (lane & 15);
#pragma unroll
  for (int m = 0; m < FM; ++m)
#pragma unroll
    for (int n = 0; n < FN; ++n)
#pragma unroll
      for (int j = 0; j < 4; ++j) {
        const int rr = rB + m * 16 + j, cc = cB + n * 16;
        const u64 ci = cOff + (u64)rr * (u32)N + (u32)cc;
        float v = acc[m][n][j];
        if constexpr (ADDMASK) v += Mask[mOff + (u64)rr * (u32)N + (u32)cc];
        if constexpr (SPLITOUT) {
          u16 h = f2bf(v);
          Chi[ci] = h;
          Clo[ci] = f2bf(v - bf2f(h));
        } else {
          Cf[ci] = v;
        }
      }
}

// --------- softmax over s (one wave per row), fp32 in (mask pre-added) -------
__global__ __launch_bounds__(256) void k_softmax(const float* __restrict__ sc,
                                                 u16* __restrict__ attn) {
  const int row = blockIdx.x * 4 + (threadIdx.x >> 6);
  const int lane = threadIdx.x & 63;
  const float* srow = sc + (u64)row * 512 + lane * 8;
  float4 s0 = *reinterpret_cast<const float4*>(srow);
  float4 s1 = *reinterpret_cast<const float4*>(srow + 4);
  float x[8] = {s0.x, s0.y, s0.z, s0.w, s1.x, s1.y, s1.z, s1.w};
  float mx = x[0];
#pragma unroll
  for (int j = 1; j < 8; ++j) mx = fmaxf(mx, x[j]);
#pragma unroll
  for (int off = 32; off > 0; off >>= 1) mx = fmaxf(mx, __shfl_xor(mx, off));
  float sum = 0.f;
#pragma unroll
  for (int j = 0; j < 8; ++j) {
    x[j] = __expf(x[j] - mx);
    sum += x[j];
  }
#pragma unroll
  for (int off = 32; off > 0; off >>= 1) sum += __shfl_xor(sum, off);
  const float inv = 1.f / sum;
  u32 o[4];
#pragma unroll
  for (int j = 0; j < 4; ++j) {
    u16 e0 = f2bf(x[2 * j] * inv), e1 = f2bf(x[2 * j + 1] * inv);
    o[j] = (u32)e0 | ((u32)e1 << 16);
  }
  *reinterpret_cast<uint4*>(attn + (u64)row * 512 + lane * 8) = make_uint4(o[0], o[1], o[2], o[3]);
}

// -----------------------------------------------------------------------------
extern "C" void kernel_launch(void* const* d_in, const int* in_sizes, int n_in,
                              void* d_out, int out_size, void* d_ws, size_t ws_size,
                              hipStream_t stream) {
  // N=4, B=8, T=512, S=512, E=1024, R=1024
  const float* q = (const float*)d_in[0];
  const float* kvs = (const float*)d_in[1];
  const float* mask = (const float*)d_in[2];
  const float* Wk = (const float*)d_in[3];  // bk unused (constant over s)
  float* out = (float*)d_out;

  char* w = (char*)d_ws;
  u16* q_hi = (u16*)(w + 0);
  u16* q_lo = (u16*)(w + 8388608);
  u16* attn = (u16*)(w + 0);            // aliases q_hi/q_lo (dead by then)
  u16* wkt_hi = (u16*)(w + 16777216);
  u16* wkt_lo = (u16*)(w + 18874368);
  u16* qp_hi = (u16*)(w + 20971520);
  u16* qp_lo = (u16*)(w + 29360128);
  u16* kv_hi = (u16*)(w + 37748736);
  u16* kv_lo = (u16*)(w + 71303168);
  u16* kvt_hi = (u16*)(w + 104857600);
  float* sc = (float*)(w + 138412032);

  // 1) split q into hi/lo bf16
  k_split4<<<dim3(4096), dim3(256), 0, stream>>>((const float4*)q, (uint2*)q_hi, (uint2*)q_lo);
  // 2) Wk [e][r] -> transposed split wkt[r][e] hi/lo
  k_trsplit64<0, 1, 1><<<dim3(16, 16, 1), dim3(256), 0, stream>>>(
      Wk, (u16*)nullptr, (u16*)nullptr, wkt_hi, wkt_lo, 1024, 1024);
  // 3) kvs -> straight split hi/lo [s][r] + transposed hi [r][s]
  k_trsplit64<1, 1, 0><<<dim3(16, 8, 32), dim3(256), 0, stream>>>(
      kvs, kv_hi, kv_lo, kvt_hi, (u16*)nullptr, 512, 1024);
  // 4) qproj[bt][r] = q[bt][e]*wkt[r][e]  (bf16x3, split-out); 2-phase, 256 blocks
  k_gemm2<1, 4, 4, 2, 2, 0, 1><<<dim3(256), dim3(256), 0, stream>>>(
      q_hi, q_lo, wkt_hi, wkt_lo, (float*)nullptr, qp_hi, qp_lo, (const float*)nullptr,
      1024, 1024, 32, 8, (u64)0, 0, (u64)0, (u64)0);
  // 5) scores[z][t][s] = qp[b][t][r]*kv[z][s][r] + mask  (bf16x3, depth-3);
  //    BM=256 BN=128 -> 2x4x32 = 256 blocks, 144KB LDS, 1 block/CU (8 waves)
  k_gemm3<1, 1, 0, 2><<<dim3(256), dim3(512), 0, stream>>>(
      qp_hi, qp_lo, kv_hi, kv_lo, sc, (u16*)nullptr, (u16*)nullptr, mask,
      1024, 512, 2, 4, (u64)524288, 7, (u64)524288, (u64)262144);
  // 6) softmax(sc) -> attn bf16
  k_softmax<<<dim3(4096), dim3(256), 0, stream>>>(sc, attn);
  // 7) out[z][t][r] = attn[z][t][s]*kvt[z][r][s]  (bf16, depth-3);
  //    BM=256 BN=128 -> 2x8x32 = 512 blocks, 72KB LDS, 2 blocks/CU
  k_gemm3<0, 0, 0, 4><<<dim3(512), dim3(512), 0, stream>>>(
      attn, (u16*)nullptr, kvt_hi, (u16*)nullptr, out, (u16*)nullptr, (u16*)nullptr,
      (const float*)nullptr, 512, 1024, 2, 8, (u64)262144, 31, (u64)524288, (u64)524288);

  (void)in_sizes; (void)n_in; (void)out_size; (void)ws_size;
}

// Round 6
// 159.086 us; speedup vs baseline: 1.2529x; 1.0885x over previous
//
#include <hip/hip_runtime.h>

typedef unsigned short u16;
typedef unsigned int u32;
typedef unsigned long long u64;

typedef __bf16 bfrag __attribute__((ext_vector_type(8)));
typedef float f32x4 __attribute__((ext_vector_type(4)));

typedef __attribute__((address_space(1))) char* gas1_p;
typedef __attribute__((address_space(3))) char* las3_p;

#define DI __device__ __forceinline__

DI u16 f2bf(float f) {
  u32 u = __float_as_uint(f);
  u += 0x7FFFu + ((u >> 16) & 1u);
  return (u16)(u >> 16);
}
DI float bf2f(u16 h) { return __uint_as_float(((u32)h) << 16); }

DI void gload16(const void* g, void* l) {
  __builtin_amdgcn_global_load_lds((gas1_p)(u64)g, (las3_p)(u32)(u64)l, 16, 0, 0);
}

// ------- 64x64 tile: straight split (hi/lo) and/or transposed (thi/tlo) ------
template <int WH, int WTH, int WTL>
__global__ __launch_bounds__(256) void k_trsplit64(const float* __restrict__ in,
                                                   u16* __restrict__ hi, u16* __restrict__ lo,
                                                   u16* __restrict__ thi, u16* __restrict__ tlo,
                                                   int rows, int cols) {
  __shared__ float tile[64][65];
  const u64 zoff = (u64)blockIdx.z * (u64)rows * (u64)cols;
  const int r0 = threadIdx.x >> 4;
  const int c4 = (threadIdx.x & 15) << 2;
  const float* src = in + zoff + (u64)(blockIdx.y * 64 + r0) * cols + blockIdx.x * 64 + c4;
#pragma unroll
  for (int p = 0; p < 4; ++p) {
    float4 v = *reinterpret_cast<const float4*>(src + (u64)(p * 16) * cols);
    tile[r0 + p * 16][c4 + 0] = v.x;
    tile[r0 + p * 16][c4 + 1] = v.y;
    tile[r0 + p * 16][c4 + 2] = v.z;
    tile[r0 + p * 16][c4 + 3] = v.w;
  }
  __syncthreads();
  if constexpr (WH) {
    const int rr = threadIdx.x >> 3;
    const int cc = (threadIdx.x & 7) << 3;
#pragma unroll
    for (int p = 0; p < 2; ++p) {
      const int r = rr + p * 32;
      u32 h[4], l[4];
#pragma unroll
      for (int j = 0; j < 4; ++j) {
        float a = tile[r][cc + 2 * j], b = tile[r][cc + 2 * j + 1];
        u16 ha = f2bf(a), hb = f2bf(b);
        h[j] = (u32)ha | ((u32)hb << 16);
        l[j] = (u32)f2bf(a - bf2f(ha)) | ((u32)f2bf(b - bf2f(hb)) << 16);
      }
      const u64 o = zoff + (u64)(blockIdx.y * 64 + r) * cols + blockIdx.x * 64 + cc;
      *reinterpret_cast<uint4*>(hi + o) = make_uint4(h[0], h[1], h[2], h[3]);
      *reinterpret_cast<uint4*>(lo + o) = make_uint4(l[0], l[1], l[2], l[3]);
    }
  }
  if constexpr (WTH) {
#pragma unroll
    for (int p = 0; p < 2; ++p) {
      const int id = threadIdx.x + p * 256;
      const int col = id >> 3;
      const int s8 = (id & 7) << 3;
      u32 h[4], l[4];
#pragma unroll
      for (int j = 0; j < 4; ++j) {
        float a = tile[s8 + 2 * j][col], b = tile[s8 + 2 * j + 1][col];
        u16 ha = f2bf(a), hb = f2bf(b);
        h[j] = (u32)ha | ((u32)hb << 16);
        if constexpr (WTL)
          l[j] = (u32)f2bf(a - bf2f(ha)) | ((u32)f2bf(b - bf2f(hb)) << 16);
      }
      const u64 o = zoff + (u64)(blockIdx.x * 64 + col) * rows + blockIdx.y * 64 + s8;
      *reinterpret_cast<uint4*>(thi + o) = make_uint4(h[0], h[1], h[2], h[3]);
      if constexpr (WTL)
        *reinterpret_cast<uint4*>(tlo + o) = make_uint4(l[0], l[1], l[2], l[3]);
    }
  }
}

// ===== unified 2-phase pipelined bt-GEMM: STAGE(next) || COMPUTE(cur) ========
// C[z][m][n] = sum_k A[z][m][k]*B[z][n][k].
// AF32/BF32: operand staged as raw f32 (144B padded rows, bank-rotating),
//   split to bf16 hi/lo IN REGISTER when building fragments (same arithmetic
//   as the pre-split path).  bf16 operands keep the k-slot XOR swizzle.
// X3: 3 MFMA passes (Ah*Bh + Ah*Bl + Al*Bh).  ADDMASK: +Mask.  SPLITOUT: hi/lo.
template <int X3, int AF32, int BF32, int FM, int FN, int WR, int WC,
          int ADDMASK, int SPLITOUT>
__global__ __launch_bounds__(WR * WC * 64, 2) void k_gemmF(
    const void* Ap, const u16* Aploi, const void* Bp, const u16* Bploi,
    float* __restrict__ Cf, u16* __restrict__ Chi, u16* __restrict__ Clo,
    const float* __restrict__ Mask,
    int K, int N, int mt, int nt,
    u64 aStride, int aMask, u64 bStride, u64 cStride) {
  constexpr int NTHR = WR * WC * 64;
  constexpr int BM = WR * FM * 16, BN = WC * FN * 16;
  // chunk counts (16B each) per K-step; f32 tiles use 9 chunks/row (144B pad)
  constexpr int ACH = AF32 ? ((BM * 9 + NTHR - 1) / NTHR) * NTHR : BM * 4;
  constexpr int BCH = BF32 ? ((BN * 9 + NTHR - 1) / NTHR) * NTHR : BN * 4;
  constexpr int A_SZ = AF32 ? ACH * 8 : BM * 32 * (1 + X3);  // u16 units
  constexpr int B_SZ = BF32 ? BCH * 8 : BN * 32 * (1 + X3);
  constexpr int AL0 = BM * 32;  // bf16 lo sub-offset
  constexpr int BL0 = BN * 32;
  constexpr int TILE = A_SZ + B_SZ;
  constexpr int CA = ACH / NTHR, CB = BCH / NTHR;
  __shared__ u16 lds[2 * TILE];

  const int tid = threadIdx.x, lane = tid & 63;
  const int wid = tid >> 6, wr = wid / WC, wc = wid % WC;

  // bijective XCD-chunked swizzle (grid divisible by 8)
  const int g = (blockIdx.x & 7) * (gridDim.x >> 3) + (blockIdx.x >> 3);
  const int z = g / (mt * nt);
  const int rem = g - z * (mt * nt);
  const int ty = rem / nt, tx = rem - ty * nt;

  const u64 aOff = (u64)(z & aMask) * aStride;
  const u64 bOff = (u64)z * bStride;
  const float* gAf = nullptr;
  const u16* gA = nullptr;
  const u16* gAl = nullptr;
  if constexpr (AF32) {
    gAf = (const float*)Ap + aOff + (u64)ty * (u32)BM * (u32)K;
  } else {
    gA = (const u16*)Ap + aOff + (u64)ty * (u32)BM * (u32)K;
    if constexpr (X3) gAl = Aploi + aOff + (u64)ty * (u32)BM * (u32)K;
  }
  const float* gBf = nullptr;
  const u16* gB = nullptr;
  const u16* gBl = nullptr;
  if constexpr (BF32) {
    gBf = (const float*)Bp + bOff + (u64)tx * (u32)BN * (u32)K;
  } else {
    gB = (const u16*)Bp + bOff + (u64)tx * (u32)BN * (u32)K;
    if constexpr (X3) gBl = Bploi + bOff + (u64)tx * (u32)BN * (u32)K;
  }

  // per-thread staging offsets (lds dest is linear in tid; source pre-mapped)
  u64 aG[CA]; u32 aLd[CA];
#pragma unroll
  for (int i = 0; i < CA; ++i) {
    const int c = i * NTHR + tid;
    if constexpr (AF32) {
      const int row = c / 9, cc = c - row * 9;
      aG[i] = (row < BM && cc < 8) ? ((u64)row * (u32)K + (u32)(cc * 4)) : 0;
      aLd[i] = c * 8;
    } else {
      const int row = c >> 2, ks = c & 3;
      aG[i] = (u64)row * (u32)K + (u32)((ks ^ ((row >> 1) & 3)) << 3);
      aLd[i] = c << 3;
    }
  }
  u64 bG[CB]; u32 bLd[CB];
#pragma unroll
  for (int i = 0; i < CB; ++i) {
    const int c = i * NTHR + tid;
    if constexpr (BF32) {
      const int row = c / 9, cc = c - row * 9;
      bG[i] = (row < BN && cc < 8) ? ((u64)row * (u32)K + (u32)(cc * 4)) : 0;
      bLd[i] = c * 8;
    } else {
      const int row = c >> 2, ks = c & 3;
      bG[i] = (u64)row * (u32)K + (u32)((ks ^ ((row >> 1) & 3)) << 3);
      bLd[i] = c << 3;
    }
  }

  f32x4 acc[FM][FN];
#pragma unroll
  for (int m = 0; m < FM; ++m)
#pragma unroll
    for (int n = 0; n < FN; ++n) acc[m][n] = (f32x4){0.f, 0.f, 0.f, 0.f};

  auto STAGE = [&](int bufU, int k0) {
#pragma unroll
    for (int i = 0; i < CA; ++i) {
      if constexpr (AF32) {
        gload16(gAf + aG[i] + (u32)k0, &lds[bufU + aLd[i]]);
      } else {
        gload16(gA + aG[i] + (u32)k0, &lds[bufU + aLd[i]]);
        if constexpr (X3) gload16(gAl + aG[i] + (u32)k0, &lds[bufU + AL0 + aLd[i]]);
      }
    }
#pragma unroll
    for (int i = 0; i < CB; ++i) {
      if constexpr (BF32) {
        gload16(gBf + bG[i] + (u32)k0, &lds[bufU + A_SZ + bLd[i]]);
      } else {
        gload16(gB + bG[i] + (u32)k0, &lds[bufU + A_SZ + bLd[i]]);
        if constexpr (X3) gload16(gBl + bG[i] + (u32)k0, &lds[bufU + A_SZ + BL0 + bLd[i]]);
      }
    }
  };

  const int swz = (((lane >> 1) & 3) ^ (lane >> 4)) << 3;  // bf16 phys k-slot*8
  auto COMPUTE = [&](int bufU) {
    bfrag ah[FM], al[FM], bh[FN], bl[FN];
#pragma unroll
    for (int m = 0; m < FM; ++m) {
      const int row = wr * (FM * 16) + m * 16 + (lane & 15);
      if constexpr (AF32) {
        const u32 base = bufU + (u32)row * 72 + (u32)(lane >> 4) * 16;
        f32x4 p0 = *reinterpret_cast<const f32x4*>(&lds[base]);
        f32x4 p1 = *reinterpret_cast<const f32x4*>(&lds[base + 8]);
#pragma unroll
        for (int j = 0; j < 8; ++j) {
          float f = j < 4 ? p0[j] : p1[j - 4];
          __bf16 h = (__bf16)f;
          ah[m][j] = h;
          al[m][j] = (__bf16)(f - (float)h);
        }
      } else {
        const int idx = bufU + row * 32 + swz;
        ah[m] = *reinterpret_cast<const bfrag*>(&lds[idx]);
        if constexpr (X3) al[m] = *reinterpret_cast<const bfrag*>(&lds[idx + AL0]);
      }
    }
#pragma unroll
    for (int n = 0; n < FN; ++n) {
      const int row = wc * (FN * 16) + n * 16 + (lane & 15);
      if constexpr (BF32) {
        const u32 base = bufU + A_SZ + (u32)row * 72 + (u32)(lane >> 4) * 16;
        f32x4 p0 = *reinterpret_cast<const f32x4*>(&lds[base]);
        f32x4 p1 = *reinterpret_cast<const f32x4*>(&lds[base + 8]);
#pragma unroll
        for (int j = 0; j < 8; ++j) {
          float f = j < 4 ? p0[j] : p1[j - 4];
          __bf16 h = (__bf16)f;
          bh[n][j] = h;
          bl[n][j] = (__bf16)(f - (float)h);
        }
      } else {
        const int idx = bufU + A_SZ + row * 32 + swz;
        bh[n] = *reinterpret_cast<const bfrag*>(&lds[idx]);
        if constexpr (X3) bl[n] = *reinterpret_cast<const bfrag*>(&lds[idx + BL0]);
      }
    }
#pragma unroll
    for (int m = 0; m < FM; ++m)
#pragma unroll
      for (int n = 0; n < FN; ++n) {
        acc[m][n] = __builtin_amdgcn_mfma_f32_16x16x32_bf16(ah[m], bh[n], acc[m][n], 0, 0, 0);
        if constexpr (X3) {
          acc[m][n] = __builtin_amdgcn_mfma_f32_16x16x32_bf16(ah[m], bl[n], acc[m][n], 0, 0, 0);
          acc[m][n] = __builtin_amdgcn_mfma_f32_16x16x32_bf16(al[m], bh[n], acc[m][n], 0, 0, 0);
        }
      }
  };

  const int NT = K >> 5;
  STAGE(0, 0);
  asm volatile("s_waitcnt vmcnt(0)" ::: "memory");
  __builtin_amdgcn_s_barrier();
  int buf = 0;
  for (int t = 0; t < NT; ++t) {
    if (t + 1 < NT) STAGE(TILE - buf, (t + 1) << 5);  // stage NEXT during COMPUTE
    COMPUTE(buf);
    if (t + 1 < NT) {
      asm volatile("s_waitcnt vmcnt(0)" ::: "memory");
      __builtin_amdgcn_s_barrier();
      buf = TILE - buf;
    }
  }

  const u64 cOff = (u64)z * cStride;
  const u64 mOff = (u64)(z & aMask) * cStride;
  const int rB = ty * BM + wr * (FM * 16) + (lane >> 4) * 4;
  const int cB = tx * BN + wc * (FN * 16) + (lane & 15);
#pragma unroll
  for (int m = 0; m < FM; ++m)
#pragma unroll
    for (int n = 0; n < FN; ++n)
#pragma unroll
      for (int j = 0; j < 4; ++j) {
        const int rr = rB + m * 16 + j, cc = cB + n * 16;
        const u64 ci = cOff + (u64)rr * (u32)N + (u32)cc;
        float v = acc[m][n][j];
        if constexpr (ADDMASK) v += Mask[mOff + (u64)rr * (u32)N + (u32)cc];
        if constexpr (SPLITOUT) {
          u16 h = f2bf(v);
          Chi[ci] = h;
          Clo[ci] = f2bf(v - bf2f(h));
        } else {
          Cf[ci] = v;
        }
      }
}

// --------- softmax over s (one wave per row), fp32 in (mask pre-added) -------
__global__ __launch_bounds__(256) void k_softmax(const float* __restrict__ sc,
                                                 u16* __restrict__ attn) {
  const int row = blockIdx.x * 4 + (threadIdx.x >> 6);
  const int lane = threadIdx.x & 63;
  const float* srow = sc + (u64)row * 512 + lane * 8;
  float4 s0 = *reinterpret_cast<const float4*>(srow);
  float4 s1 = *reinterpret_cast<const float4*>(srow + 4);
  float x[8] = {s0.x, s0.y, s0.z, s0.w, s1.x, s1.y, s1.z, s1.w};
  float mx = x[0];
#pragma unroll
  for (int j = 1; j < 8; ++j) mx = fmaxf(mx, x[j]);
#pragma unroll
  for (int off = 32; off > 0; off >>= 1) mx = fmaxf(mx, __shfl_xor(mx, off));
  float sum = 0.f;
#pragma unroll
  for (int j = 0; j < 8; ++j) {
    x[j] = __expf(x[j] - mx);
    sum += x[j];
  }
#pragma unroll
  for (int off = 32; off > 0; off >>= 1) sum += __shfl_xor(sum, off);
  const float inv = 1.f / sum;
  u32 o[4];
#pragma unroll
  for (int j = 0; j < 4; ++j) {
    u16 e0 = f2bf(x[2 * j] * inv), e1 = f2bf(x[2 * j + 1] * inv);
    o[j] = (u32)e0 | ((u32)e1 << 16);
  }
  *reinterpret_cast<uint4*>(attn + (u64)row * 512 + lane * 8) = make_uint4(o[0], o[1], o[2], o[3]);
}

// -----------------------------------------------------------------------------
extern "C" void kernel_launch(void* const* d_in, const int* in_sizes, int n_in,
                              void* d_out, int out_size, void* d_ws, size_t ws_size,
                              hipStream_t stream) {
  // N=4, B=8, T=512, S=512, E=1024, R=1024
  const float* q = (const float*)d_in[0];     // [1,8,512,1024] f32
  const float* kvs = (const float*)d_in[1];   // [4,8,512,1024] f32
  const float* mask = (const float*)d_in[2];  // [1,8,512,512]  f32
  const float* Wk = (const float*)d_in[3];    // [1024,1024]    (bk unused)
  float* out = (float*)d_out;                 // [4,8,512,1024] f32

  char* w = (char*)d_ws;
  u16* attn = (u16*)(w + 0);            // 16.8 MiB [32][512][512]
  u16* wkt_hi = (u16*)(w + 16777216);   //  2 MiB   [1024 r][1024 e]
  u16* wkt_lo = (u16*)(w + 18874368);
  u16* qp_hi = (u16*)(w + 20971520);    //  8 MiB   [8][512][1024] (b,t,r)
  u16* qp_lo = (u16*)(w + 29360128);
  u16* kvt_hi = (u16*)(w + 104857600);  // 32 MiB   [32][1024][512] (z,r,s)
  float* sc = (float*)(w + 138412032);  // 32 MiB   [32][512][512]  (z,t,s)

  // 1) Wk [e][r] -> transposed split wkt[r][e] hi/lo
  k_trsplit64<0, 1, 1><<<dim3(16, 16, 1), dim3(256), 0, stream>>>(
      Wk, (u16*)nullptr, (u16*)nullptr, wkt_hi, wkt_lo, 1024, 1024);
  // 2) kvs -> transposed hi only: kvt[z][r][s]  (no straight split anymore)
  k_trsplit64<0, 1, 0><<<dim3(16, 8, 32), dim3(256), 0, stream>>>(
      kvs, (u16*)nullptr, (u16*)nullptr, kvt_hi, (u16*)nullptr, 512, 1024);
  // 3) qproj[bt][r] = q[bt][e]*wkt[r][e]; A = raw f32 q (in-reg split), x3,
  //    split-out; 128x128 tiles, 256 blocks
  k_gemmF<1, 1, 0, 4, 4, 2, 2, 0, 1><<<dim3(256), dim3(256), 0, stream>>>(
      q, (const u16*)nullptr, wkt_hi, wkt_lo,
      (float*)nullptr, qp_hi, qp_lo, (const float*)nullptr,
      1024, 1024, 32, 8, (u64)0, 0, (u64)0, (u64)0);
  // 4) scores[z][t][s] = qp[b][t][r]*kvs[z][s][r] + mask; B = raw f32 kvs
  //    (in-reg split), x3; 128x128 tiles, 512 blocks
  k_gemmF<1, 0, 1, 4, 4, 2, 2, 1, 0><<<dim3(512), dim3(256), 0, stream>>>(
      qp_hi, qp_lo, kvs, (const u16*)nullptr,
      sc, (u16*)nullptr, (u16*)nullptr, mask,
      1024, 512, 4, 4, (u64)524288, 7, (u64)524288, (u64)262144);
  // 5) softmax(sc) -> attn bf16
  k_softmax<<<dim3(4096), dim3(256), 0, stream>>>(sc, attn);
  // 6) out[z][t][r] = attn[z][t][s]*kvt[z][r][s]; pure bf16 x1; 256x128, 512 blk
  k_gemmF<0, 0, 0, 8, 4, 2, 2, 0, 0><<<dim3(512), dim3(256), 0, stream>>>(
      attn, (const u16*)nullptr, kvt_hi, (const u16*)nullptr,
      out, (u16*)nullptr, (u16*)nullptr, (const float*)nullptr,
      512, 1024, 2, 8, (u64)262144, 31, (u64)524288, (u64)524288);

  (void)in_sizes; (void)n_in; (void)out_size; (void)ws_size;
}